// Round 1
// baseline (1128.497 us; speedup 1.0000x reference)
//
#include <hip/hip_runtime.h>

// ---------------------------------------------------------------------------
// GATv2 (2 layers) + mean-pool + MLP for MI355X. fp32 throughout.
// N=50000 nodes, E=800000 edges (+N self loops), IN=128, HID=64, HEADS=2,
// OUT=3, 64 graphs. Output: [64,3] float32.
// ---------------------------------------------------------------------------

#define NGRAPH 64

static constexpr unsigned ENC_NEG = 0x007FFFFFu; // enc(-inf)

__device__ __forceinline__ unsigned enc_f32(float x) {
  unsigned u = __float_as_uint(x);
  return (u & 0x80000000u) ? ~u : (u | 0x80000000u);
}
__device__ __forceinline__ float dec_f32(unsigned u) {
  return __uint_as_float((u & 0x80000000u) ? (u & 0x7FFFFFFFu) : ~u);
}
__device__ __forceinline__ void edge_sd(const int* __restrict__ ei, int E, int e,
                                        int& s, int& d) {
  if (e < E) { s = ei[e]; d = ei[E + e]; }
  else       { s = e - E; d = s; }
}

// ---------------------------------------------------------------------------
__global__ void k_init(int* __restrict__ deg, int* __restrict__ cursor,
                       float* __restrict__ denom1, unsigned* __restrict__ amax1,
                       float* __restrict__ denom2, unsigned* __restrict__ amax2,
                       float* __restrict__ gsum, float* __restrict__ gcnt, int N) {
  int i = blockIdx.x * blockDim.x + threadIdx.x;
  if (i < N) { deg[i] = 0; cursor[i] = 0; denom2[i] = 0.f; amax2[i] = ENC_NEG; }
  if (i < 2 * N) { denom1[i] = 0.f; amax1[i] = ENC_NEG; }
  if (i < NGRAPH * 3) gsum[i] = 0.f;
  if (i < NGRAPH) gcnt[i] = 0.f;
}

__global__ void k_deg(const int* __restrict__ ei, int E, int Et, int* __restrict__ deg) {
  int e = blockIdx.x * blockDim.x + threadIdx.x;
  if (e >= Et) return;
  int s, d; edge_sd(ei, E, e, s, d);
  atomicAdd(&deg[d], 1);
}

// single block, 1024 threads: exclusive scan of deg -> row_ptr[0..n]
__global__ __launch_bounds__(1024) void k_scan(const int* __restrict__ deg,
                                               int* __restrict__ row_ptr, int n) {
  __shared__ int sdata[1024];
  int t = threadIdx.x;
  int chunk = (n + 1023) >> 10;
  int base = t * chunk;
  int end = min(base + chunk, n);
  int sum = 0;
  for (int i = base; i < end; ++i) sum += deg[i];
  sdata[t] = sum;
  __syncthreads();
  for (int off = 1; off < 1024; off <<= 1) {
    int v = (t >= off) ? sdata[t - off] : 0;
    __syncthreads();
    sdata[t] += v;
    __syncthreads();
  }
  int run = sdata[t] - sum;  // exclusive prefix of this chunk
  for (int i = base; i < end; ++i) { row_ptr[i] = run; run += deg[i]; }
  if (t == 1023) row_ptr[n] = sdata[1023];
}

__global__ void k_fill(const int* __restrict__ ei, int E, int Et,
                       const int* __restrict__ row_ptr, int* __restrict__ cursor,
                       int* __restrict__ csr_src, int* __restrict__ csr_eid) {
  int e = blockIdx.x * blockDim.x + threadIdx.x;
  if (e >= Et) return;
  int s, d; edge_sd(ei, E, e, s, d);
  int pos = atomicAdd(&cursor[d], 1);
  int slot = row_ptr[d] + pos;
  csr_src[slot] = s;
  csr_eid[slot] = e;
}

// ---------------------------------------------------------------------------
// out[n,128] = x[n,128] @ W[128,128]. Block: 256 thr, 16 rows, W in LDS.
__global__ __launch_bounds__(256) void k_gemm128(const float* __restrict__ x,
                                                 const float* __restrict__ W,
                                                 float* __restrict__ out, int n) {
  __shared__ __align__(16) float Ws[128 * 128];
  __shared__ __align__(16) float xs[16][132];
  int tid = threadIdx.x;
  const float4* W4 = (const float4*)W;
  float4* Ws4 = (float4*)Ws;
  for (int i = tid; i < 128 * 32; i += 256) Ws4[i] = W4[i];
  int r0 = blockIdx.x * 16;
  for (int i = tid; i < 16 * 32; i += 256) {
    int r = i >> 5, c4 = (i & 31) * 4;
    float4 v = make_float4(0.f, 0.f, 0.f, 0.f);
    if (r0 + r < n) v = *(const float4*)&x[(size_t)(r0 + r) * 128 + c4];
    xs[r][c4 + 0] = v.x; xs[r][c4 + 1] = v.y; xs[r][c4 + 2] = v.z; xs[r][c4 + 3] = v.w;
  }
  __syncthreads();
  int j = (tid & 31) * 4;
  int rp = tid >> 5;  // 0..7 -> rows rp, rp+8
  float a0x = 0.f, a0y = 0.f, a0z = 0.f, a0w = 0.f;
  float a1x = 0.f, a1y = 0.f, a1z = 0.f, a1w = 0.f;
#pragma unroll 8
  for (int k = 0; k < 128; ++k) {
    float4 w = *(const float4*)&Ws[k * 128 + j];
    float x0 = xs[rp][k], x1 = xs[rp + 8][k];
    a0x = fmaf(x0, w.x, a0x); a0y = fmaf(x0, w.y, a0y);
    a0z = fmaf(x0, w.z, a0z); a0w = fmaf(x0, w.w, a0w);
    a1x = fmaf(x1, w.x, a1x); a1y = fmaf(x1, w.y, a1y);
    a1z = fmaf(x1, w.z, a1z); a1w = fmaf(x1, w.w, a1w);
  }
  int r = r0 + rp;
  if (r < n) *(float4*)&out[(size_t)r * 128 + j] = make_float4(a0x, a0y, a0z, a0w);
  r = r0 + rp + 8;
  if (r < n) *(float4*)&out[(size_t)r * 128 + j] = make_float4(a1x, a1y, a1z, a1w);
}

// ---------------------------------------------------------------------------
// one wave per edge: alpha logits (2 heads) + atomicMax into amax
__global__ __launch_bounds__(256) void k_alpha1(const float* __restrict__ xl,
                                                const float* __restrict__ xr,
                                                const int* __restrict__ ei, int E, int Et,
                                                const float* __restrict__ att1,
                                                float* __restrict__ alpha,
                                                unsigned* __restrict__ amax) {
  int gw = (blockIdx.x * 256 + threadIdx.x) >> 6;
  int lane = threadIdx.x & 63;
  if (gw >= Et) return;
  int s, d; edge_sd(ei, E, gw, s, d);
  float t0 = xl[(size_t)s * 128 + lane] + xr[(size_t)d * 128 + lane];
  float t1 = xl[(size_t)s * 128 + 64 + lane] + xr[(size_t)d * 128 + 64 + lane];
  t0 = (t0 > 0.f ? t0 : 0.2f * t0) * att1[lane];
  t1 = (t1 > 0.f ? t1 : 0.2f * t1) * att1[64 + lane];
#pragma unroll
  for (int off = 32; off; off >>= 1) {
    t0 += __shfl_xor(t0, off);
    t1 += __shfl_xor(t1, off);
  }
  if (lane == 0) {
    alpha[gw * 2] = t0;
    alpha[gw * 2 + 1] = t1;
    atomicMax(&amax[d * 2], enc_f32(t0));
    atomicMax(&amax[d * 2 + 1], enc_f32(t1));
  }
}

__global__ void k_exp1(const int* __restrict__ ei, int E, int Et,
                       float* __restrict__ alpha, const unsigned* __restrict__ amax,
                       float* __restrict__ denom) {
  int id = blockIdx.x * blockDim.x + threadIdx.x;
  if (id >= Et * 2) return;
  int e = id >> 1, h = id & 1;
  int s, d; edge_sd(ei, E, e, s, d);
  float ea = expf(alpha[id] - dec_f32(amax[d * 2 + h]));
  alpha[id] = ea;
  atomicAdd(&denom[d * 2 + h], ea);
}

// one block (128 thr) per node: out[n,c] = elu( sum_e w*xl[src,c] + b1[c] )
__global__ __launch_bounds__(128) void k_agg1(const float* __restrict__ xl,
                                              const float* __restrict__ ea,
                                              const float* __restrict__ denom,
                                              const int* __restrict__ row_ptr,
                                              const int* __restrict__ csr_src,
                                              const int* __restrict__ csr_eid,
                                              const float* __restrict__ b1,
                                              float* __restrict__ hout) {
  int n = blockIdx.x;
  int c = threadIdx.x;
  int h = c >> 6;
  float inv = 1.f / (denom[n * 2 + h] + 1e-16f);
  int s0 = row_ptr[n], s1 = row_ptr[n + 1];
  float acc = 0.f;
  for (int slot = s0; slot < s1; ++slot) {
    int s = csr_src[slot];
    int eid = csr_eid[slot];
    acc = fmaf(ea[eid * 2 + h], xl[(size_t)s * 128 + c], acc);
  }
  acc = acc * inv + b1[c];
  hout[(size_t)n * 128 + c] = acc > 0.f ? acc : expm1f(acc);
}

// one wave per node: xl2/xr2 [n,3] = h[n,:] @ W2l/W2r (128x3)
__global__ __launch_bounds__(256) void k_gemm2(const float* __restrict__ h,
                                               const float* __restrict__ W2l,
                                               const float* __restrict__ W2r,
                                               float* __restrict__ xl2,
                                               float* __restrict__ xr2, int n) {
  int node = (blockIdx.x * 256 + threadIdx.x) >> 6;
  int lane = threadIdx.x & 63;
  if (node >= n) return;
  float h0 = h[(size_t)node * 128 + lane];
  float h1 = h[(size_t)node * 128 + 64 + lane];
  float al[3], ar[3];
#pragma unroll
  for (int j = 0; j < 3; ++j) {
    al[j] = h0 * W2l[lane * 3 + j] + h1 * W2l[(64 + lane) * 3 + j];
    ar[j] = h0 * W2r[lane * 3 + j] + h1 * W2r[(64 + lane) * 3 + j];
  }
#pragma unroll
  for (int off = 32; off; off >>= 1) {
#pragma unroll
    for (int j = 0; j < 3; ++j) {
      al[j] += __shfl_xor(al[j], off);
      ar[j] += __shfl_xor(ar[j], off);
    }
  }
  if (lane == 0) {
#pragma unroll
    for (int j = 0; j < 3; ++j) {
      xl2[node * 3 + j] = al[j];
      xr2[node * 3 + j] = ar[j];
    }
  }
}

__global__ void k_alpha2(const float* __restrict__ xl2, const float* __restrict__ xr2,
                         const int* __restrict__ ei, int E, int Et,
                         const float* __restrict__ att2, float* __restrict__ alpha,
                         unsigned* __restrict__ amax) {
  int e = blockIdx.x * blockDim.x + threadIdx.x;
  if (e >= Et) return;
  int s, d; edge_sd(ei, E, e, s, d);
  float a = 0.f;
#pragma unroll
  for (int j = 0; j < 3; ++j) {
    float t = xl2[s * 3 + j] + xr2[d * 3 + j];
    t = (t > 0.f ? t : 0.2f * t);
    a = fmaf(t, att2[j], a);
  }
  alpha[e] = a;
  atomicMax(&amax[d], enc_f32(a));
}

__global__ void k_exp2(const int* __restrict__ ei, int E, int Et,
                       float* __restrict__ alpha, const unsigned* __restrict__ amax,
                       float* __restrict__ denom) {
  int e = blockIdx.x * blockDim.x + threadIdx.x;
  if (e >= Et) return;
  int s, d; edge_sd(ei, E, e, s, d);
  float ea = expf(alpha[e] - dec_f32(amax[d]));
  alpha[e] = ea;
  atomicAdd(&denom[d], ea);
}

// thread per node: aggregate layer-2 messages, add b2, pool into graphs
__global__ void k_agg2(const float* __restrict__ xl2, const float* __restrict__ ea,
                       const float* __restrict__ denom, const int* __restrict__ row_ptr,
                       const int* __restrict__ csr_src, const int* __restrict__ csr_eid,
                       const float* __restrict__ b2, const int* __restrict__ batch,
                       float* __restrict__ gsum, float* __restrict__ gcnt, int n) {
  int node = blockIdx.x * blockDim.x + threadIdx.x;
  if (node >= n) return;
  float inv = 1.f / (denom[node] + 1e-16f);
  float a0 = 0.f, a1 = 0.f, a2 = 0.f;
  int s0 = row_ptr[node], s1 = row_ptr[node + 1];
  for (int slot = s0; slot < s1; ++slot) {
    int s = csr_src[slot];
    float w = ea[csr_eid[slot]];
    a0 = fmaf(w, xl2[s * 3 + 0], a0);
    a1 = fmaf(w, xl2[s * 3 + 1], a1);
    a2 = fmaf(w, xl2[s * 3 + 2], a2);
  }
  a0 = a0 * inv + b2[0];
  a1 = a1 * inv + b2[1];
  a2 = a2 * inv + b2[2];
  int b = batch[node];
  atomicAdd(&gsum[b * 3 + 0], a0);
  atomicAdd(&gsum[b * 3 + 1], a1);
  atomicAdd(&gsum[b * 3 + 2], a2);
  atomicAdd(&gcnt[b], 1.f);
}

// 1 block, 64 threads: per-graph mean + 2-layer MLP
__global__ __launch_bounds__(64) void k_mlp(const float* __restrict__ gsum,
                                            const float* __restrict__ gcnt,
                                            const float* __restrict__ Wr1,
                                            const float* __restrict__ br1,
                                            const float* __restrict__ Wr2,
                                            const float* __restrict__ br2,
                                            float* __restrict__ out) {
  int t = threadIdx.x;
  if (t >= NGRAPH) return;
  float cnt = fmaxf(gcnt[t], 1.f);
  float g0 = gsum[t * 3 + 0] / cnt;
  float g1 = gsum[t * 3 + 1] / cnt;
  float g2 = gsum[t * 3 + 2] / cnt;
  float o0 = br2[0], o1 = br2[1], o2 = br2[2];
  for (int j = 0; j < 64; ++j) {
    float hj = g0 * Wr1[j] + g1 * Wr1[64 + j] + g2 * Wr1[128 + j] + br1[j];
    hj = fmaxf(hj, 0.f);
    o0 = fmaf(hj, Wr2[j * 3 + 0], o0);
    o1 = fmaf(hj, Wr2[j * 3 + 1], o1);
    o2 = fmaf(hj, Wr2[j * 3 + 2], o2);
  }
  out[t * 3 + 0] = o0;
  out[t * 3 + 1] = o1;
  out[t * 3 + 2] = o2;
}

// ---------------------------------------------------------------------------
extern "C" void kernel_launch(void* const* d_in, const int* in_sizes, int n_in,
                              void* d_out, int out_size, void* d_ws, size_t ws_size,
                              hipStream_t stream) {
  const float* x    = (const float*)d_in[0];
  const int*   ei   = (const int*)d_in[1];
  const int*   batch= (const int*)d_in[2];
  const float* W1l  = (const float*)d_in[3];
  const float* W1r  = (const float*)d_in[4];
  const float* att1 = (const float*)d_in[5];
  const float* b1   = (const float*)d_in[6];
  const float* W2l  = (const float*)d_in[7];
  const float* W2r  = (const float*)d_in[8];
  const float* att2 = (const float*)d_in[9];
  const float* b2   = (const float*)d_in[10];
  const float* Wr1  = (const float*)d_in[11];
  const float* br1  = (const float*)d_in[12];
  const float* Wr2  = (const float*)d_in[13];
  const float* br2  = (const float*)d_in[14];
  float* out = (float*)d_out;

  const int N  = in_sizes[0] / 128;
  const int E  = in_sizes[1] / 2;
  const int Et = E + N;

  char* p = (char*)d_ws;
  auto alloc = [&](size_t bytes) -> char* {
    char* r = p;
    p += (bytes + 255) & ~(size_t)255;
    return r;
  };
  float*    xl1    = (float*)alloc((size_t)N * 128 * 4);
  float*    xr1    = (float*)alloc((size_t)N * 128 * 4);  // later reused as h
  float*    ea1    = (float*)alloc((size_t)Et * 2 * 4);
  unsigned* amax1  = (unsigned*)alloc((size_t)N * 2 * 4);
  float*    denom1 = (float*)alloc((size_t)N * 2 * 4);
  int*      row_ptr= (int*)alloc((size_t)(N + 1) * 4);
  int*      deg    = (int*)alloc((size_t)N * 4);
  int*      cursor = (int*)alloc((size_t)N * 4);
  int*      csr_src= (int*)alloc((size_t)Et * 4);
  int*      csr_eid= (int*)alloc((size_t)Et * 4);
  float*    xl2    = (float*)alloc((size_t)N * 3 * 4);
  float*    xr2    = (float*)alloc((size_t)N * 3 * 4);
  float*    ea2    = (float*)alloc((size_t)Et * 4);
  unsigned* amax2  = (unsigned*)alloc((size_t)N * 4);
  float*    denom2 = (float*)alloc((size_t)N * 4);
  float*    gsum   = (float*)alloc(NGRAPH * 3 * 4);
  float*    gcnt   = (float*)alloc(NGRAPH * 4);
  float*    h      = xr1;  // alias: xr1 dead after k_alpha1

  hipLaunchKernelGGL(k_init, dim3((2 * N + 255) / 256), dim3(256), 0, stream,
                     deg, cursor, denom1, amax1, denom2, amax2, gsum, gcnt, N);
  hipLaunchKernelGGL(k_deg, dim3((Et + 255) / 256), dim3(256), 0, stream, ei, E, Et, deg);
  hipLaunchKernelGGL(k_scan, dim3(1), dim3(1024), 0, stream, deg, row_ptr, N);
  hipLaunchKernelGGL(k_fill, dim3((Et + 255) / 256), dim3(256), 0, stream,
                     ei, E, Et, row_ptr, cursor, csr_src, csr_eid);
  hipLaunchKernelGGL(k_gemm128, dim3((N + 15) / 16), dim3(256), 0, stream, x, W1l, xl1, N);
  hipLaunchKernelGGL(k_gemm128, dim3((N + 15) / 16), dim3(256), 0, stream, x, W1r, xr1, N);
  hipLaunchKernelGGL(k_alpha1, dim3((Et + 3) / 4), dim3(256), 0, stream,
                     xl1, xr1, ei, E, Et, att1, ea1, amax1);
  hipLaunchKernelGGL(k_exp1, dim3((2 * Et + 255) / 256), dim3(256), 0, stream,
                     ei, E, Et, ea1, amax1, denom1);
  hipLaunchKernelGGL(k_agg1, dim3(N), dim3(128), 0, stream,
                     xl1, ea1, denom1, row_ptr, csr_src, csr_eid, b1, h);
  hipLaunchKernelGGL(k_gemm2, dim3((N + 3) / 4), dim3(256), 0, stream,
                     h, W2l, W2r, xl2, xr2, N);
  hipLaunchKernelGGL(k_alpha2, dim3((Et + 255) / 256), dim3(256), 0, stream,
                     xl2, xr2, ei, E, Et, att2, ea2, amax2);
  hipLaunchKernelGGL(k_exp2, dim3((Et + 255) / 256), dim3(256), 0, stream,
                     ei, E, Et, ea2, amax2, denom2);
  hipLaunchKernelGGL(k_agg2, dim3((N + 255) / 256), dim3(256), 0, stream,
                     xl2, ea2, denom2, row_ptr, csr_src, csr_eid, b2, batch,
                     gsum, gcnt, N);
  hipLaunchKernelGGL(k_mlp, dim3(1), dim3(64), 0, stream,
                     gsum, gcnt, Wr1, br1, Wr2, br2, out);
}

// Round 2
// 803.410 us; speedup vs baseline: 1.4046x; 1.4046x over previous
//
#include <hip/hip_runtime.h>

// ---------------------------------------------------------------------------
// GATv2 (2 layers) + mean-pool + MLP for MI355X. fp32 throughout.
// N=50000 nodes, E=800000 edges (+N self loops), IN=128, HID=64, HEADS=2,
// OUT=3, 64 graphs. Output: [64,3] float32.
// R1: k_agg2 was 351us (top dispatch) — pool atomic storm (50k waves x 4
//     same-address device atomics onto 256 addrs) + 1-thread-per-node serial
//     gather. Now: 16 lanes/node gather + LDS pool pre-reduction per block.
// ---------------------------------------------------------------------------

#define NGRAPH 64

static constexpr unsigned ENC_NEG = 0x007FFFFFu; // enc(-inf)

__device__ __forceinline__ unsigned enc_f32(float x) {
  unsigned u = __float_as_uint(x);
  return (u & 0x80000000u) ? ~u : (u | 0x80000000u);
}
__device__ __forceinline__ float dec_f32(unsigned u) {
  return __uint_as_float((u & 0x80000000u) ? (u & 0x7FFFFFFFu) : ~u);
}
__device__ __forceinline__ void edge_sd(const int* __restrict__ ei, int E, int e,
                                        int& s, int& d) {
  if (e < E) { s = ei[e]; d = ei[E + e]; }
  else       { s = e - E; d = s; }
}

// ---------------------------------------------------------------------------
__global__ void k_init(int* __restrict__ deg, int* __restrict__ cursor,
                       float* __restrict__ denom1, unsigned* __restrict__ amax1,
                       float* __restrict__ denom2, unsigned* __restrict__ amax2,
                       float* __restrict__ gsum, float* __restrict__ gcnt, int N) {
  int i = blockIdx.x * blockDim.x + threadIdx.x;
  if (i < N) { deg[i] = 0; cursor[i] = 0; denom2[i] = 0.f; amax2[i] = ENC_NEG; }
  if (i < 2 * N) { denom1[i] = 0.f; amax1[i] = ENC_NEG; }
  if (i < NGRAPH * 3) gsum[i] = 0.f;
  if (i < NGRAPH) gcnt[i] = 0.f;
}

__global__ void k_deg(const int* __restrict__ ei, int E, int Et, int* __restrict__ deg) {
  int e = blockIdx.x * blockDim.x + threadIdx.x;
  if (e >= Et) return;
  int s, d; edge_sd(ei, E, e, s, d);
  atomicAdd(&deg[d], 1);
}

// single block, 1024 threads: exclusive scan of deg -> row_ptr[0..n]
__global__ __launch_bounds__(1024) void k_scan(const int* __restrict__ deg,
                                               int* __restrict__ row_ptr, int n) {
  __shared__ int sdata[1024];
  int t = threadIdx.x;
  int chunk = (n + 1023) >> 10;
  int base = t * chunk;
  int end = min(base + chunk, n);
  int sum = 0;
  for (int i = base; i < end; ++i) sum += deg[i];
  sdata[t] = sum;
  __syncthreads();
  for (int off = 1; off < 1024; off <<= 1) {
    int v = (t >= off) ? sdata[t - off] : 0;
    __syncthreads();
    sdata[t] += v;
    __syncthreads();
  }
  int run = sdata[t] - sum;  // exclusive prefix of this chunk
  for (int i = base; i < end; ++i) { row_ptr[i] = run; run += deg[i]; }
  if (t == 1023) row_ptr[n] = sdata[1023];
}

__global__ void k_fill(const int* __restrict__ ei, int E, int Et,
                       const int* __restrict__ row_ptr, int* __restrict__ cursor,
                       int* __restrict__ csr_src, int* __restrict__ csr_eid) {
  int e = blockIdx.x * blockDim.x + threadIdx.x;
  if (e >= Et) return;
  int s, d; edge_sd(ei, E, e, s, d);
  int pos = atomicAdd(&cursor[d], 1);
  int slot = row_ptr[d] + pos;
  csr_src[slot] = s;
  csr_eid[slot] = e;
}

// ---------------------------------------------------------------------------
// out[n,128] = x[n,128] @ W[128,128]. Block: 256 thr, 16 rows, W in LDS.
__global__ __launch_bounds__(256) void k_gemm128(const float* __restrict__ x,
                                                 const float* __restrict__ W,
                                                 float* __restrict__ out, int n) {
  __shared__ __align__(16) float Ws[128 * 128];
  __shared__ __align__(16) float xs[16][132];
  int tid = threadIdx.x;
  const float4* W4 = (const float4*)W;
  float4* Ws4 = (float4*)Ws;
  for (int i = tid; i < 128 * 32; i += 256) Ws4[i] = W4[i];
  int r0 = blockIdx.x * 16;
  for (int i = tid; i < 16 * 32; i += 256) {
    int r = i >> 5, c4 = (i & 31) * 4;
    float4 v = make_float4(0.f, 0.f, 0.f, 0.f);
    if (r0 + r < n) v = *(const float4*)&x[(size_t)(r0 + r) * 128 + c4];
    xs[r][c4 + 0] = v.x; xs[r][c4 + 1] = v.y; xs[r][c4 + 2] = v.z; xs[r][c4 + 3] = v.w;
  }
  __syncthreads();
  int j = (tid & 31) * 4;
  int rp = tid >> 5;  // 0..7 -> rows rp, rp+8
  float a0x = 0.f, a0y = 0.f, a0z = 0.f, a0w = 0.f;
  float a1x = 0.f, a1y = 0.f, a1z = 0.f, a1w = 0.f;
#pragma unroll 8
  for (int k = 0; k < 128; ++k) {
    float4 w = *(const float4*)&Ws[k * 128 + j];
    float x0 = xs[rp][k], x1 = xs[rp + 8][k];
    a0x = fmaf(x0, w.x, a0x); a0y = fmaf(x0, w.y, a0y);
    a0z = fmaf(x0, w.z, a0z); a0w = fmaf(x0, w.w, a0w);
    a1x = fmaf(x1, w.x, a1x); a1y = fmaf(x1, w.y, a1y);
    a1z = fmaf(x1, w.z, a1z); a1w = fmaf(x1, w.w, a1w);
  }
  int r = r0 + rp;
  if (r < n) *(float4*)&out[(size_t)r * 128 + j] = make_float4(a0x, a0y, a0z, a0w);
  r = r0 + rp + 8;
  if (r < n) *(float4*)&out[(size_t)r * 128 + j] = make_float4(a1x, a1y, a1z, a1w);
}

// ---------------------------------------------------------------------------
// one wave per edge: alpha logits (2 heads) + atomicMax into amax
__global__ __launch_bounds__(256) void k_alpha1(const float* __restrict__ xl,
                                                const float* __restrict__ xr,
                                                const int* __restrict__ ei, int E, int Et,
                                                const float* __restrict__ att1,
                                                float* __restrict__ alpha,
                                                unsigned* __restrict__ amax) {
  int gw = (blockIdx.x * 256 + threadIdx.x) >> 6;
  int lane = threadIdx.x & 63;
  if (gw >= Et) return;
  int s, d; edge_sd(ei, E, gw, s, d);
  float t0 = xl[(size_t)s * 128 + lane] + xr[(size_t)d * 128 + lane];
  float t1 = xl[(size_t)s * 128 + 64 + lane] + xr[(size_t)d * 128 + 64 + lane];
  t0 = (t0 > 0.f ? t0 : 0.2f * t0) * att1[lane];
  t1 = (t1 > 0.f ? t1 : 0.2f * t1) * att1[64 + lane];
#pragma unroll
  for (int off = 32; off; off >>= 1) {
    t0 += __shfl_xor(t0, off);
    t1 += __shfl_xor(t1, off);
  }
  if (lane == 0) {
    alpha[gw * 2] = t0;
    alpha[gw * 2 + 1] = t1;
    atomicMax(&amax[d * 2], enc_f32(t0));
    atomicMax(&amax[d * 2 + 1], enc_f32(t1));
  }
}

__global__ void k_exp1(const int* __restrict__ ei, int E, int Et,
                       float* __restrict__ alpha, const unsigned* __restrict__ amax,
                       float* __restrict__ denom) {
  int id = blockIdx.x * blockDim.x + threadIdx.x;
  if (id >= Et * 2) return;
  int e = id >> 1, h = id & 1;
  int s, d; edge_sd(ei, E, e, s, d);
  float ea = expf(alpha[id] - dec_f32(amax[d * 2 + h]));
  alpha[id] = ea;
  atomicAdd(&denom[d * 2 + h], ea);
}

// one block (128 thr) per node: out[n,c] = elu( sum_e w*xl[src,c] + b1[c] )
__global__ __launch_bounds__(128) void k_agg1(const float* __restrict__ xl,
                                              const float* __restrict__ ea,
                                              const float* __restrict__ denom,
                                              const int* __restrict__ row_ptr,
                                              const int* __restrict__ csr_src,
                                              const int* __restrict__ csr_eid,
                                              const float* __restrict__ b1,
                                              float* __restrict__ hout) {
  int n = blockIdx.x;
  int c = threadIdx.x;
  int h = c >> 6;
  float inv = 1.f / (denom[n * 2 + h] + 1e-16f);
  int s0 = row_ptr[n], s1 = row_ptr[n + 1];
  float acc = 0.f;
  for (int slot = s0; slot < s1; ++slot) {
    int s = csr_src[slot];
    int eid = csr_eid[slot];
    acc = fmaf(ea[eid * 2 + h], xl[(size_t)s * 128 + c], acc);
  }
  acc = acc * inv + b1[c];
  hout[(size_t)n * 128 + c] = acc > 0.f ? acc : expm1f(acc);
}

// one wave per node: xl2/xr2 [n,3] = h[n,:] @ W2l/W2r (128x3)
__global__ __launch_bounds__(256) void k_gemm2(const float* __restrict__ h,
                                               const float* __restrict__ W2l,
                                               const float* __restrict__ W2r,
                                               float* __restrict__ xl2,
                                               float* __restrict__ xr2, int n) {
  int node = (blockIdx.x * 256 + threadIdx.x) >> 6;
  int lane = threadIdx.x & 63;
  if (node >= n) return;
  float h0 = h[(size_t)node * 128 + lane];
  float h1 = h[(size_t)node * 128 + 64 + lane];
  float al[3], ar[3];
#pragma unroll
  for (int j = 0; j < 3; ++j) {
    al[j] = h0 * W2l[lane * 3 + j] + h1 * W2l[(64 + lane) * 3 + j];
    ar[j] = h0 * W2r[lane * 3 + j] + h1 * W2r[(64 + lane) * 3 + j];
  }
#pragma unroll
  for (int off = 32; off; off >>= 1) {
#pragma unroll
    for (int j = 0; j < 3; ++j) {
      al[j] += __shfl_xor(al[j], off);
      ar[j] += __shfl_xor(ar[j], off);
    }
  }
  if (lane == 0) {
#pragma unroll
    for (int j = 0; j < 3; ++j) {
      xl2[node * 3 + j] = al[j];
      xr2[node * 3 + j] = ar[j];
    }
  }
}

__global__ void k_alpha2(const float* __restrict__ xl2, const float* __restrict__ xr2,
                         const int* __restrict__ ei, int E, int Et,
                         const float* __restrict__ att2, float* __restrict__ alpha,
                         unsigned* __restrict__ amax) {
  int e = blockIdx.x * blockDim.x + threadIdx.x;
  if (e >= Et) return;
  int s, d; edge_sd(ei, E, e, s, d);
  float a = 0.f;
#pragma unroll
  for (int j = 0; j < 3; ++j) {
    float t = xl2[s * 3 + j] + xr2[d * 3 + j];
    t = (t > 0.f ? t : 0.2f * t);
    a = fmaf(t, att2[j], a);
  }
  alpha[e] = a;
  atomicMax(&amax[d], enc_f32(a));
}

__global__ void k_exp2(const int* __restrict__ ei, int E, int Et,
                       float* __restrict__ alpha, const unsigned* __restrict__ amax,
                       float* __restrict__ denom) {
  int e = blockIdx.x * blockDim.x + threadIdx.x;
  if (e >= Et) return;
  int s, d; edge_sd(ei, E, e, s, d);
  float ea = expf(alpha[e] - dec_f32(amax[d]));
  alpha[e] = ea;
  atomicAdd(&denom[d], ea);
}

// ---------------------------------------------------------------------------
// R1 rewrite: 16 lanes per node gather (parallel over in-edges, shfl reduce),
// fused mean-pool with LDS per-block pre-reduction (kills the 200k global
// same-address atomic storm -> ~25k spread atomics).
__global__ __launch_bounds__(256) void k_agg2(const float* __restrict__ xl2,
                                              const float* __restrict__ ea,
                                              const float* __restrict__ denom,
                                              const int* __restrict__ row_ptr,
                                              const int* __restrict__ csr_src,
                                              const int* __restrict__ csr_eid,
                                              const float* __restrict__ b2,
                                              const int* __restrict__ batch,
                                              float* __restrict__ gsum,
                                              float* __restrict__ gcnt, int n) {
  __shared__ float ls[NGRAPH * 3];
  __shared__ float lc[NGRAPH];
  int t = threadIdx.x;
  for (int i = t; i < NGRAPH * 3; i += 256) ls[i] = 0.f;
  for (int i = t; i < NGRAPH; i += 256) lc[i] = 0.f;
  __syncthreads();

  int node = (blockIdx.x * 256 + t) >> 4;  // 16 nodes per block
  int lane = t & 15;
  if (node < n) {
    int s0 = row_ptr[node], s1 = row_ptr[node + 1];
    float a0 = 0.f, a1 = 0.f, a2 = 0.f;
    for (int slot = s0 + lane; slot < s1; slot += 16) {
      int s = csr_src[slot];
      float w = ea[csr_eid[slot]];
      a0 = fmaf(w, xl2[s * 3 + 0], a0);
      a1 = fmaf(w, xl2[s * 3 + 1], a1);
      a2 = fmaf(w, xl2[s * 3 + 2], a2);
    }
#pragma unroll
    for (int off = 8; off; off >>= 1) {
      a0 += __shfl_xor(a0, off);
      a1 += __shfl_xor(a1, off);
      a2 += __shfl_xor(a2, off);
    }
    if (lane == 0) {
      float inv = 1.f / (denom[node] + 1e-16f);
      a0 = a0 * inv + b2[0];
      a1 = a1 * inv + b2[1];
      a2 = a2 * inv + b2[2];
      int b = batch[node];
      atomicAdd(&ls[b * 3 + 0], a0);
      atomicAdd(&ls[b * 3 + 1], a1);
      atomicAdd(&ls[b * 3 + 2], a2);
      atomicAdd(&lc[b], 1.f);
    }
  }
  __syncthreads();
  for (int i = t; i < NGRAPH * 3; i += 256)
    if (ls[i] != 0.f) atomicAdd(&gsum[i], ls[i]);
  for (int i = t; i < NGRAPH; i += 256)
    if (lc[i] != 0.f) atomicAdd(&gcnt[i], lc[i]);
}

// 1 block, 64 threads: per-graph mean + 2-layer MLP
__global__ __launch_bounds__(64) void k_mlp(const float* __restrict__ gsum,
                                            const float* __restrict__ gcnt,
                                            const float* __restrict__ Wr1,
                                            const float* __restrict__ br1,
                                            const float* __restrict__ Wr2,
                                            const float* __restrict__ br2,
                                            float* __restrict__ out) {
  int t = threadIdx.x;
  if (t >= NGRAPH) return;
  float cnt = fmaxf(gcnt[t], 1.f);
  float g0 = gsum[t * 3 + 0] / cnt;
  float g1 = gsum[t * 3 + 1] / cnt;
  float g2 = gsum[t * 3 + 2] / cnt;
  float o0 = br2[0], o1 = br2[1], o2 = br2[2];
  for (int j = 0; j < 64; ++j) {
    float hj = g0 * Wr1[j] + g1 * Wr1[64 + j] + g2 * Wr1[128 + j] + br1[j];
    hj = fmaxf(hj, 0.f);
    o0 = fmaf(hj, Wr2[j * 3 + 0], o0);
    o1 = fmaf(hj, Wr2[j * 3 + 1], o1);
    o2 = fmaf(hj, Wr2[j * 3 + 2], o2);
  }
  out[t * 3 + 0] = o0;
  out[t * 3 + 1] = o1;
  out[t * 3 + 2] = o2;
}

// ---------------------------------------------------------------------------
extern "C" void kernel_launch(void* const* d_in, const int* in_sizes, int n_in,
                              void* d_out, int out_size, void* d_ws, size_t ws_size,
                              hipStream_t stream) {
  const float* x    = (const float*)d_in[0];
  const int*   ei   = (const int*)d_in[1];
  const int*   batch= (const int*)d_in[2];
  const float* W1l  = (const float*)d_in[3];
  const float* W1r  = (const float*)d_in[4];
  const float* att1 = (const float*)d_in[5];
  const float* b1   = (const float*)d_in[6];
  const float* W2l  = (const float*)d_in[7];
  const float* W2r  = (const float*)d_in[8];
  const float* att2 = (const float*)d_in[9];
  const float* b2   = (const float*)d_in[10];
  const float* Wr1  = (const float*)d_in[11];
  const float* br1  = (const float*)d_in[12];
  const float* Wr2  = (const float*)d_in[13];
  const float* br2  = (const float*)d_in[14];
  float* out = (float*)d_out;

  const int N  = in_sizes[0] / 128;
  const int E  = in_sizes[1] / 2;
  const int Et = E + N;

  char* p = (char*)d_ws;
  auto alloc = [&](size_t bytes) -> char* {
    char* r = p;
    p += (bytes + 255) & ~(size_t)255;
    return r;
  };
  float*    xl1    = (float*)alloc((size_t)N * 128 * 4);
  float*    xr1    = (float*)alloc((size_t)N * 128 * 4);  // later reused as h
  float*    ea1    = (float*)alloc((size_t)Et * 2 * 4);
  unsigned* amax1  = (unsigned*)alloc((size_t)N * 2 * 4);
  float*    denom1 = (float*)alloc((size_t)N * 2 * 4);
  int*      row_ptr= (int*)alloc((size_t)(N + 1) * 4);
  int*      deg    = (int*)alloc((size_t)N * 4);
  int*      cursor = (int*)alloc((size_t)N * 4);
  int*      csr_src= (int*)alloc((size_t)Et * 4);
  int*      csr_eid= (int*)alloc((size_t)Et * 4);
  float*    xl2    = (float*)alloc((size_t)N * 3 * 4);
  float*    xr2    = (float*)alloc((size_t)N * 3 * 4);
  float*    ea2    = (float*)alloc((size_t)Et * 4);
  unsigned* amax2  = (unsigned*)alloc((size_t)N * 4);
  float*    denom2 = (float*)alloc((size_t)N * 4);
  float*    gsum   = (float*)alloc(NGRAPH * 3 * 4);
  float*    gcnt   = (float*)alloc(NGRAPH * 4);
  float*    h      = xr1;  // alias: xr1 dead after k_alpha1

  hipLaunchKernelGGL(k_init, dim3((2 * N + 255) / 256), dim3(256), 0, stream,
                     deg, cursor, denom1, amax1, denom2, amax2, gsum, gcnt, N);
  hipLaunchKernelGGL(k_deg, dim3((Et + 255) / 256), dim3(256), 0, stream, ei, E, Et, deg);
  hipLaunchKernelGGL(k_scan, dim3(1), dim3(1024), 0, stream, deg, row_ptr, N);
  hipLaunchKernelGGL(k_fill, dim3((Et + 255) / 256), dim3(256), 0, stream,
                     ei, E, Et, row_ptr, cursor, csr_src, csr_eid);
  hipLaunchKernelGGL(k_gemm128, dim3((N + 15) / 16), dim3(256), 0, stream, x, W1l, xl1, N);
  hipLaunchKernelGGL(k_gemm128, dim3((N + 15) / 16), dim3(256), 0, stream, x, W1r, xr1, N);
  hipLaunchKernelGGL(k_alpha1, dim3((Et + 3) / 4), dim3(256), 0, stream,
                     xl1, xr1, ei, E, Et, att1, ea1, amax1);
  hipLaunchKernelGGL(k_exp1, dim3((2 * Et + 255) / 256), dim3(256), 0, stream,
                     ei, E, Et, ea1, amax1, denom1);
  hipLaunchKernelGGL(k_agg1, dim3(N), dim3(128), 0, stream,
                     xl1, ea1, denom1, row_ptr, csr_src, csr_eid, b1, h);
  hipLaunchKernelGGL(k_gemm2, dim3((N + 3) / 4), dim3(256), 0, stream,
                     h, W2l, W2r, xl2, xr2, N);
  hipLaunchKernelGGL(k_alpha2, dim3((Et + 255) / 256), dim3(256), 0, stream,
                     xl2, xr2, ei, E, Et, att2, ea2, amax2);
  hipLaunchKernelGGL(k_exp2, dim3((Et + 255) / 256), dim3(256), 0, stream,
                     ei, E, Et, ea2, amax2, denom2);
  hipLaunchKernelGGL(k_agg2, dim3((N * 16 + 255) / 256), dim3(256), 0, stream,
                     xl2, ea2, denom2, row_ptr, csr_src, csr_eid, b2, batch,
                     gsum, gcnt, N);
  hipLaunchKernelGGL(k_mlp, dim3(1), dim3(64), 0, stream,
                     gsum, gcnt, Wr1, br1, Wr2, br2, out);
}

// Round 3
// 515.033 us; speedup vs baseline: 2.1911x; 1.5599x over previous
//
#include <hip/hip_runtime.h>

// ---------------------------------------------------------------------------
// GATv2 (2 layers) + mean-pool + MLP for MI355X. fp32 throughout.
// N=50000 nodes, E=800000 edges (+N self loops), IN=128, HID=64, HEADS=2,
// OUT=3, 64 graphs. Output: [64,3] float32.
// R1: k_agg2 pool atomic storm fixed (LDS pre-reduction). 1128 -> 803 us.
// R2: edge phase fused. k_alpha1 (181us) + k_exp1 + k_agg1 were 3 passes over
//     the 435MB random xl[src] gather with global softmax atomics. Now: CSR +
//     per-node ONLINE softmax (flash-style) -> single pass, no atomics
//     (k_fused1). Same for layer 2 (k_fused2 = gather+softmax+agg+pool).
// ---------------------------------------------------------------------------

#define NGRAPH 64

__device__ __forceinline__ void edge_sd(const int* __restrict__ ei, int E, int e,
                                        int& s, int& d) {
  if (e < E) { s = ei[e]; d = ei[E + e]; }
  else       { s = e - E; d = s; }
}

// ---------------------------------------------------------------------------
__global__ void k_init(int* __restrict__ deg, int* __restrict__ cursor,
                       float* __restrict__ gsum, float* __restrict__ gcnt, int N) {
  int i = blockIdx.x * blockDim.x + threadIdx.x;
  if (i < N) { deg[i] = 0; cursor[i] = 0; }
  if (i < NGRAPH * 3) gsum[i] = 0.f;
  if (i < NGRAPH) gcnt[i] = 0.f;
}

__global__ void k_deg(const int* __restrict__ ei, int E, int Et, int* __restrict__ deg) {
  int e = blockIdx.x * blockDim.x + threadIdx.x;
  if (e >= Et) return;
  int s, d; edge_sd(ei, E, e, s, d);
  atomicAdd(&deg[d], 1);
}

// single block, 1024 threads: exclusive scan of deg -> row_ptr[0..n]
__global__ __launch_bounds__(1024) void k_scan(const int* __restrict__ deg,
                                               int* __restrict__ row_ptr, int n) {
  __shared__ int sdata[1024];
  int t = threadIdx.x;
  int chunk = (n + 1023) >> 10;
  int base = t * chunk;
  int end = min(base + chunk, n);
  int sum = 0;
  for (int i = base; i < end; ++i) sum += deg[i];
  sdata[t] = sum;
  __syncthreads();
  for (int off = 1; off < 1024; off <<= 1) {
    int v = (t >= off) ? sdata[t - off] : 0;
    __syncthreads();
    sdata[t] += v;
    __syncthreads();
  }
  int run = sdata[t] - sum;  // exclusive prefix of this chunk
  for (int i = base; i < end; ++i) { row_ptr[i] = run; run += deg[i]; }
  if (t == 1023) row_ptr[n] = sdata[1023];
}

__global__ void k_fill(const int* __restrict__ ei, int E, int Et,
                       const int* __restrict__ row_ptr, int* __restrict__ cursor,
                       int* __restrict__ csr_src) {
  int e = blockIdx.x * blockDim.x + threadIdx.x;
  if (e >= Et) return;
  int s, d; edge_sd(ei, E, e, s, d);
  int pos = atomicAdd(&cursor[d], 1);
  csr_src[row_ptr[d] + pos] = s;
}

// ---------------------------------------------------------------------------
// out[n,128] = x[n,128] @ W[128,128]. Block: 256 thr, 16 rows, W in LDS.
__global__ __launch_bounds__(256) void k_gemm128(const float* __restrict__ x,
                                                 const float* __restrict__ W,
                                                 float* __restrict__ out, int n) {
  __shared__ __align__(16) float Ws[128 * 128];
  __shared__ __align__(16) float xs[16][132];
  int tid = threadIdx.x;
  const float4* W4 = (const float4*)W;
  float4* Ws4 = (float4*)Ws;
  for (int i = tid; i < 128 * 32; i += 256) Ws4[i] = W4[i];
  int r0 = blockIdx.x * 16;
  for (int i = tid; i < 16 * 32; i += 256) {
    int r = i >> 5, c4 = (i & 31) * 4;
    float4 v = make_float4(0.f, 0.f, 0.f, 0.f);
    if (r0 + r < n) v = *(const float4*)&x[(size_t)(r0 + r) * 128 + c4];
    xs[r][c4 + 0] = v.x; xs[r][c4 + 1] = v.y; xs[r][c4 + 2] = v.z; xs[r][c4 + 3] = v.w;
  }
  __syncthreads();
  int j = (tid & 31) * 4;
  int rp = tid >> 5;  // 0..7 -> rows rp, rp+8
  float a0x = 0.f, a0y = 0.f, a0z = 0.f, a0w = 0.f;
  float a1x = 0.f, a1y = 0.f, a1z = 0.f, a1w = 0.f;
#pragma unroll 8
  for (int k = 0; k < 128; ++k) {
    float4 w = *(const float4*)&Ws[k * 128 + j];
    float x0 = xs[rp][k], x1 = xs[rp + 8][k];
    a0x = fmaf(x0, w.x, a0x); a0y = fmaf(x0, w.y, a0y);
    a0z = fmaf(x0, w.z, a0z); a0w = fmaf(x0, w.w, a0w);
    a1x = fmaf(x1, w.x, a1x); a1y = fmaf(x1, w.y, a1y);
    a1z = fmaf(x1, w.z, a1z); a1w = fmaf(x1, w.w, a1w);
  }
  int r = r0 + rp;
  if (r < n) *(float4*)&out[(size_t)r * 128 + j] = make_float4(a0x, a0y, a0z, a0w);
  r = r0 + rp + 8;
  if (r < n) *(float4*)&out[(size_t)r * 128 + j] = make_float4(a1x, a1y, a1z, a1w);
}

// ---------------------------------------------------------------------------
// R2: fused layer-1 edge phase. One 64-lane wave per dst node; lane holds
// channels {2*lane, 2*lane+1} (lanes 0..31 = head 0, 32..63 = head 1).
// Per in-edge: float2 gather of xl[src], leakyrelu+att dot via half-wave
// shfl reduce, ONLINE softmax rescale of (m, l, acc). No atomics, one pass.
__global__ __launch_bounds__(256) void k_fused1(const float* __restrict__ xl,
                                                const float* __restrict__ xr,
                                                const int* __restrict__ row_ptr,
                                                const int* __restrict__ csr_src,
                                                const float* __restrict__ att1,
                                                const float* __restrict__ b1,
                                                float* __restrict__ hout, int n) {
  int node = (blockIdx.x * 256 + threadIdx.x) >> 6;
  int lane = threadIdx.x & 63;
  if (node >= n) return;
  int c = lane * 2;
  float2 xrv = *(const float2*)&xr[(size_t)node * 128 + c];
  float at0 = att1[c], at1 = att1[c + 1];
  int s0 = row_ptr[node], s1 = row_ptr[node + 1];
  float m = -1e30f, l = 0.f, acc0 = 0.f, acc1 = 0.f;
  for (int slot = s0; slot < s1; ++slot) {
    int s = csr_src[slot];
    s = __builtin_amdgcn_readfirstlane(s);
    float2 xlv = *(const float2*)&xl[(size_t)s * 128 + c];
    float t0 = xlv.x + xrv.x; t0 = (t0 > 0.f ? t0 : 0.2f * t0) * at0;
    float t1 = xlv.y + xrv.y; t1 = (t1 > 0.f ? t1 : 0.2f * t1) * at1;
    float p = t0 + t1;
#pragma unroll
    for (int off = 16; off; off >>= 1) p += __shfl_xor(p, off);
    // p uniform within each 32-lane half = this head's logit for the edge
    float mn = fmaxf(m, p);
    float sc = __expf(m - mn);
    float w  = __expf(p - mn);
    acc0 = acc0 * sc + w * xlv.x;
    acc1 = acc1 * sc + w * xlv.y;
    l = l * sc + w;
    m = mn;
  }
  float inv = 1.f / (l + 1e-16f);
  float o0 = acc0 * inv + b1[c];
  float o1 = acc1 * inv + b1[c + 1];
  o0 = o0 > 0.f ? o0 : expm1f(o0);
  o1 = o1 > 0.f ? o1 : expm1f(o1);
  *(float2*)&hout[(size_t)node * 128 + c] = make_float2(o0, o1);
}

// one wave per node: xl2/xr2 [n,4] (stride 4, .w=0) = h[n,:] @ W2l/W2r (128x3)
__global__ __launch_bounds__(256) void k_gemm2(const float* __restrict__ h,
                                               const float* __restrict__ W2l,
                                               const float* __restrict__ W2r,
                                               float* __restrict__ xl2,
                                               float* __restrict__ xr2, int n) {
  int node = (blockIdx.x * 256 + threadIdx.x) >> 6;
  int lane = threadIdx.x & 63;
  if (node >= n) return;
  float h0 = h[(size_t)node * 128 + lane];
  float h1 = h[(size_t)node * 128 + 64 + lane];
  float al[3], ar[3];
#pragma unroll
  for (int j = 0; j < 3; ++j) {
    al[j] = h0 * W2l[lane * 3 + j] + h1 * W2l[(64 + lane) * 3 + j];
    ar[j] = h0 * W2r[lane * 3 + j] + h1 * W2r[(64 + lane) * 3 + j];
  }
#pragma unroll
  for (int off = 32; off; off >>= 1) {
#pragma unroll
    for (int j = 0; j < 3; ++j) {
      al[j] += __shfl_xor(al[j], off);
      ar[j] += __shfl_xor(ar[j], off);
    }
  }
  if (lane == 0) {
    *(float4*)&xl2[node * 4] = make_float4(al[0], al[1], al[2], 0.f);
    *(float4*)&xr2[node * 4] = make_float4(ar[0], ar[1], ar[2], 0.f);
  }
}

// ---------------------------------------------------------------------------
// R2: fused layer-2 edge phase + mean-pool. 16 lanes per node; each lane runs
// its own online softmax over a 16-stride slice of the node's in-edges, then
// the 16 partial (m,l,acc3) states merge via shfl. Pool pre-reduced in LDS.
__global__ __launch_bounds__(256) void k_fused2(const float* __restrict__ xl2,
                                                const float* __restrict__ xr2,
                                                const int* __restrict__ row_ptr,
                                                const int* __restrict__ csr_src,
                                                const float* __restrict__ att2,
                                                const float* __restrict__ b2,
                                                const int* __restrict__ batch,
                                                float* __restrict__ gsum,
                                                float* __restrict__ gcnt, int n) {
  __shared__ float ls[NGRAPH * 3];
  __shared__ float lc[NGRAPH];
  int t = threadIdx.x;
  for (int i = t; i < NGRAPH * 3; i += 256) ls[i] = 0.f;
  for (int i = t; i < NGRAPH; i += 256) lc[i] = 0.f;
  __syncthreads();

  int node = (blockIdx.x * 256 + t) >> 4;  // 16 nodes per block
  int lane = t & 15;
  if (node < n) {
    float4 xrv = *(const float4*)&xr2[node * 4];
    float c0 = att2[0], c1 = att2[1], c2 = att2[2];
    int s0 = row_ptr[node], s1 = row_ptr[node + 1];
    float m = -1e30f, l = 0.f, a0 = 0.f, a1 = 0.f, a2 = 0.f;
    for (int slot = s0 + lane; slot < s1; slot += 16) {
      int s = csr_src[slot];
      float4 xlv = *(const float4*)&xl2[s * 4];
      float t0 = xlv.x + xrv.x; t0 = t0 > 0.f ? t0 : 0.2f * t0;
      float t1 = xlv.y + xrv.y; t1 = t1 > 0.f ? t1 : 0.2f * t1;
      float t2 = xlv.z + xrv.z; t2 = t2 > 0.f ? t2 : 0.2f * t2;
      float p = t0 * c0 + t1 * c1 + t2 * c2;
      float mn = fmaxf(m, p);
      float sc = __expf(m - mn);
      float w  = __expf(p - mn);
      a0 = a0 * sc + w * xlv.x;
      a1 = a1 * sc + w * xlv.y;
      a2 = a2 * sc + w * xlv.z;
      l = l * sc + w;
      m = mn;
    }
    // merge 16 per-lane online-softmax states (sentinel -1e30 keeps empty
    // lanes NaN-free: exp(-1e30 - -1e30) = 1 but l=0, acc=0 contribute 0)
#pragma unroll
    for (int off = 8; off; off >>= 1) {
      float m2 = __shfl_xor(m, off);
      float l2 = __shfl_xor(l, off);
      float b0 = __shfl_xor(a0, off);
      float b1v = __shfl_xor(a1, off);
      float b2v = __shfl_xor(a2, off);
      float mn = fmaxf(m, m2);
      float sA = __expf(m - mn);
      float sB = __expf(m2 - mn);
      a0 = a0 * sA + b0 * sB;
      a1 = a1 * sA + b1v * sB;
      a2 = a2 * sA + b2v * sB;
      l = l * sA + l2 * sB;
      m = mn;
    }
    if (lane == 0) {
      float inv = 1.f / (l + 1e-16f);
      float o0 = a0 * inv + b2[0];
      float o1 = a1 * inv + b2[1];
      float o2 = a2 * inv + b2[2];
      int b = batch[node];
      atomicAdd(&ls[b * 3 + 0], o0);
      atomicAdd(&ls[b * 3 + 1], o1);
      atomicAdd(&ls[b * 3 + 2], o2);
      atomicAdd(&lc[b], 1.f);
    }
  }
  __syncthreads();
  for (int i = t; i < NGRAPH * 3; i += 256)
    if (ls[i] != 0.f) atomicAdd(&gsum[i], ls[i]);
  for (int i = t; i < NGRAPH; i += 256)
    if (lc[i] != 0.f) atomicAdd(&gcnt[i], lc[i]);
}

// 1 block, 64 threads: per-graph mean + 2-layer MLP
__global__ __launch_bounds__(64) void k_mlp(const float* __restrict__ gsum,
                                            const float* __restrict__ gcnt,
                                            const float* __restrict__ Wr1,
                                            const float* __restrict__ br1,
                                            const float* __restrict__ Wr2,
                                            const float* __restrict__ br2,
                                            float* __restrict__ out) {
  int t = threadIdx.x;
  if (t >= NGRAPH) return;
  float cnt = fmaxf(gcnt[t], 1.f);
  float g0 = gsum[t * 3 + 0] / cnt;
  float g1 = gsum[t * 3 + 1] / cnt;
  float g2 = gsum[t * 3 + 2] / cnt;
  float o0 = br2[0], o1 = br2[1], o2 = br2[2];
  for (int j = 0; j < 64; ++j) {
    float hj = g0 * Wr1[j] + g1 * Wr1[64 + j] + g2 * Wr1[128 + j] + br1[j];
    hj = fmaxf(hj, 0.f);
    o0 = fmaf(hj, Wr2[j * 3 + 0], o0);
    o1 = fmaf(hj, Wr2[j * 3 + 1], o1);
    o2 = fmaf(hj, Wr2[j * 3 + 2], o2);
  }
  out[t * 3 + 0] = o0;
  out[t * 3 + 1] = o1;
  out[t * 3 + 2] = o2;
}

// ---------------------------------------------------------------------------
extern "C" void kernel_launch(void* const* d_in, const int* in_sizes, int n_in,
                              void* d_out, int out_size, void* d_ws, size_t ws_size,
                              hipStream_t stream) {
  const float* x    = (const float*)d_in[0];
  const int*   ei   = (const int*)d_in[1];
  const int*   batch= (const int*)d_in[2];
  const float* W1l  = (const float*)d_in[3];
  const float* W1r  = (const float*)d_in[4];
  const float* att1 = (const float*)d_in[5];
  const float* b1   = (const float*)d_in[6];
  const float* W2l  = (const float*)d_in[7];
  const float* W2r  = (const float*)d_in[8];
  const float* att2 = (const float*)d_in[9];
  const float* b2   = (const float*)d_in[10];
  const float* Wr1  = (const float*)d_in[11];
  const float* br1  = (const float*)d_in[12];
  const float* Wr2  = (const float*)d_in[13];
  const float* br2  = (const float*)d_in[14];
  float* out = (float*)d_out;

  const int N  = in_sizes[0] / 128;
  const int E  = in_sizes[1] / 2;
  const int Et = E + N;

  char* p = (char*)d_ws;
  auto alloc = [&](size_t bytes) -> char* {
    char* r = p;
    p += (bytes + 255) & ~(size_t)255;
    return r;
  };
  float*    xl1    = (float*)alloc((size_t)N * 128 * 4);
  float*    xr1    = (float*)alloc((size_t)N * 128 * 4);  // reused as h
  int*      row_ptr= (int*)alloc((size_t)(N + 1) * 4);
  int*      deg    = (int*)alloc((size_t)N * 4);
  int*      cursor = (int*)alloc((size_t)N * 4);
  int*      csr_src= (int*)alloc((size_t)Et * 4);
  float*    xl2    = (float*)alloc((size_t)N * 4 * 4);
  float*    xr2    = (float*)alloc((size_t)N * 4 * 4);
  float*    gsum   = (float*)alloc(NGRAPH * 3 * 4);
  float*    gcnt   = (float*)alloc(NGRAPH * 4);
  // h aliases xr1: in k_fused1 each wave reads only xr[its own node] (once,
  // before any write) and writes only h[its own node] -> race-free.
  float*    h      = xr1;

  hipLaunchKernelGGL(k_init, dim3((N + 255) / 256), dim3(256), 0, stream,
                     deg, cursor, gsum, gcnt, N);
  hipLaunchKernelGGL(k_deg, dim3((Et + 255) / 256), dim3(256), 0, stream, ei, E, Et, deg);
  hipLaunchKernelGGL(k_scan, dim3(1), dim3(1024), 0, stream, deg, row_ptr, N);
  hipLaunchKernelGGL(k_fill, dim3((Et + 255) / 256), dim3(256), 0, stream,
                     ei, E, Et, row_ptr, cursor, csr_src);
  hipLaunchKernelGGL(k_gemm128, dim3((N + 15) / 16), dim3(256), 0, stream, x, W1l, xl1, N);
  hipLaunchKernelGGL(k_gemm128, dim3((N + 15) / 16), dim3(256), 0, stream, x, W1r, xr1, N);
  hipLaunchKernelGGL(k_fused1, dim3((N + 3) / 4), dim3(256), 0, stream,
                     xl1, xr1, row_ptr, csr_src, att1, b1, h, N);
  hipLaunchKernelGGL(k_gemm2, dim3((N + 3) / 4), dim3(256), 0, stream,
                     h, W2l, W2r, xl2, xr2, N);
  hipLaunchKernelGGL(k_fused2, dim3((N * 16 + 255) / 256), dim3(256), 0, stream,
                     xl2, xr2, row_ptr, csr_src, att2, b2, batch, gsum, gcnt, N);
  hipLaunchKernelGGL(k_mlp, dim3(1), dim3(64), 0, stream,
                     gsum, gcnt, Wr1, br1, Wr2, br2, out);
}

// Round 4
// 394.074 us; speedup vs baseline: 2.8637x; 1.3069x over previous
//
#include <hip/hip_runtime.h>

// ---------------------------------------------------------------------------
// GATv2 (2 layers) + mean-pool + MLP for MI355X. fp32 throughout.
// N=50000 nodes, E=800000 edges (+N self loops), IN=128, HID=64, HEADS=2,
// OUT=3, 64 graphs. Output: [64,3] float32.
// R1: k_agg2 pool atomic storm fixed (LDS pre-reduction). 1128 -> 803 us.
// R2: CSR + per-node online softmax; edge phases fused.   803 -> 515 us.
// R3: k_fused1 (125us, issue/latency-bound: serial per-edge chain) ->
//     2-edge ILP unroll, src list register-cached per wave, layer-2 input
//     projection (old k_gemm2) fused into the epilogue (h buffer + 51MB
//     traffic + 1 launch eliminated). k_scan loads int4-ized.
// ---------------------------------------------------------------------------

#define NGRAPH 64

__device__ __forceinline__ void edge_sd(const int* __restrict__ ei, int E, int e,
                                        int& s, int& d) {
  if (e < E) { s = ei[e]; d = ei[E + e]; }
  else       { s = e - E; d = s; }
}

// ---------------------------------------------------------------------------
__global__ void k_init(int* __restrict__ deg, int* __restrict__ cursor,
                       float* __restrict__ gsum, float* __restrict__ gcnt, int N) {
  int i = blockIdx.x * blockDim.x + threadIdx.x;
  if (i < N) { deg[i] = 0; cursor[i] = 0; }
  if (i < NGRAPH * 3) gsum[i] = 0.f;
  if (i < NGRAPH) gcnt[i] = 0.f;
}

__global__ void k_deg(const int* __restrict__ ei, int E, int Et, int* __restrict__ deg) {
  int e = blockIdx.x * blockDim.x + threadIdx.x;
  if (e >= Et) return;
  int s, d; edge_sd(ei, E, e, s, d);
  atomicAdd(&deg[d], 1);
}

// single block, 1024 threads: exclusive scan of deg -> row_ptr[0..n]
// R3: int4 loads/stores (52 elems = 13 int4 per thread).
__global__ __launch_bounds__(1024) void k_scan(const int* __restrict__ deg,
                                               int* __restrict__ row_ptr, int n) {
  __shared__ int sdata[1024];
  int t = threadIdx.x;
  const int chunk = 52;
  int base = t * chunk;
  int end = min(base + chunk, n);
  int sum = 0;
  if (base + chunk <= n) {
#pragma unroll
    for (int i = 0; i < 13; ++i) {
      int4 d = *(const int4*)&deg[base + i * 4];
      sum += d.x + d.y + d.z + d.w;
    }
  } else {
    for (int i = base; i < end; ++i) sum += deg[i];
  }
  sdata[t] = sum;
  __syncthreads();
  for (int off = 1; off < 1024; off <<= 1) {
    int v = (t >= off) ? sdata[t - off] : 0;
    __syncthreads();
    sdata[t] += v;
    __syncthreads();
  }
  int run = sdata[t] - sum;  // exclusive prefix of this chunk
  if (base + chunk <= n) {
#pragma unroll
    for (int i = 0; i < 13; ++i) {
      int4 d = *(const int4*)&deg[base + i * 4];
      int4 r;
      r.x = run;       r.y = run + d.x;
      r.z = r.y + d.y; r.w = r.z + d.z;
      *(int4*)&row_ptr[base + i * 4] = r;
      run = r.w + d.w;
    }
  } else {
    for (int i = base; i < end; ++i) { row_ptr[i] = run; run += deg[i]; }
  }
  if (t == 1023) row_ptr[n] = sdata[1023];
}

__global__ void k_fill(const int* __restrict__ ei, int E, int Et,
                       const int* __restrict__ row_ptr, int* __restrict__ cursor,
                       int* __restrict__ csr_src) {
  int e = blockIdx.x * blockDim.x + threadIdx.x;
  if (e >= Et) return;
  int s, d; edge_sd(ei, E, e, s, d);
  int pos = atomicAdd(&cursor[d], 1);
  csr_src[row_ptr[d] + pos] = s;
}

// ---------------------------------------------------------------------------
// out[n,128] = x[n,128] @ W[128,128]. Block: 256 thr, 16 rows, W in LDS.
__global__ __launch_bounds__(256) void k_gemm128(const float* __restrict__ x,
                                                 const float* __restrict__ W,
                                                 float* __restrict__ out, int n) {
  __shared__ __align__(16) float Ws[128 * 128];
  __shared__ __align__(16) float xs[16][132];
  int tid = threadIdx.x;
  const float4* W4 = (const float4*)W;
  float4* Ws4 = (float4*)Ws;
  for (int i = tid; i < 128 * 32; i += 256) Ws4[i] = W4[i];
  int r0 = blockIdx.x * 16;
  for (int i = tid; i < 16 * 32; i += 256) {
    int r = i >> 5, c4 = (i & 31) * 4;
    float4 v = make_float4(0.f, 0.f, 0.f, 0.f);
    if (r0 + r < n) v = *(const float4*)&x[(size_t)(r0 + r) * 128 + c4];
    xs[r][c4 + 0] = v.x; xs[r][c4 + 1] = v.y; xs[r][c4 + 2] = v.z; xs[r][c4 + 3] = v.w;
  }
  __syncthreads();
  int j = (tid & 31) * 4;
  int rp = tid >> 5;  // 0..7 -> rows rp, rp+8
  float a0x = 0.f, a0y = 0.f, a0z = 0.f, a0w = 0.f;
  float a1x = 0.f, a1y = 0.f, a1z = 0.f, a1w = 0.f;
#pragma unroll 8
  for (int k = 0; k < 128; ++k) {
    float4 w = *(const float4*)&Ws[k * 128 + j];
    float x0 = xs[rp][k], x1 = xs[rp + 8][k];
    a0x = fmaf(x0, w.x, a0x); a0y = fmaf(x0, w.y, a0y);
    a0z = fmaf(x0, w.z, a0z); a0w = fmaf(x0, w.w, a0w);
    a1x = fmaf(x1, w.x, a1x); a1y = fmaf(x1, w.y, a1y);
    a1z = fmaf(x1, w.z, a1z); a1w = fmaf(x1, w.w, a1w);
  }
  int r = r0 + rp;
  if (r < n) *(float4*)&out[(size_t)r * 128 + j] = make_float4(a0x, a0y, a0z, a0w);
  r = r0 + rp + 8;
  if (r < n) *(float4*)&out[(size_t)r * 128 + j] = make_float4(a1x, a1y, a1z, a1w);
}

// ---------------------------------------------------------------------------
// R3: fused layer-1 edge phase + layer-2 input projection.
// One 64-lane wave per dst node; lane holds channels {2l, 2l+1}
// (lanes 0..31 = head 0, 32..63 = head 1). Src indices are loaded once per
// 64 edges (coalesced) and broadcast via shfl. Edges processed 2 at a time:
// two independent gather+reduce chains, one merged online-softmax update.
// Epilogue: ELU, then h @ W2l / h @ W2r (3+3 cols) via 6 wave reductions.
__global__ __launch_bounds__(256) void k_fused1(const float* __restrict__ xl,
                                                const float* __restrict__ xr,
                                                const int* __restrict__ row_ptr,
                                                const int* __restrict__ csr_src,
                                                const float* __restrict__ att1,
                                                const float* __restrict__ b1,
                                                const float* __restrict__ W2l,
                                                const float* __restrict__ W2r,
                                                float* __restrict__ xl2,
                                                float* __restrict__ xr2, int n) {
  int node = (blockIdx.x * 256 + threadIdx.x) >> 6;
  int lane = threadIdx.x & 63;
  if (node >= n) return;
  int c = lane * 2;
  float2 xrv = *(const float2*)&xr[(size_t)node * 128 + c];
  float at0 = att1[c], at1 = att1[c + 1];
  int s0 = row_ptr[node], s1 = row_ptr[node + 1];
  float m = -1e30f, l = 0.f, acc0 = 0.f, acc1 = 0.f;
  for (int base = s0; base < s1; base += 64) {
    int cnt = min(64, s1 - base);
    int srcs = (lane < cnt) ? csr_src[base + lane] : 0;
    int i = 0;
    for (; i + 1 < cnt; i += 2) {
      int sa = __builtin_amdgcn_readfirstlane(__shfl(srcs, i));
      int sb = __builtin_amdgcn_readfirstlane(__shfl(srcs, i + 1));
      float2 xa = *(const float2*)&xl[(size_t)sa * 128 + c];
      float2 xb = *(const float2*)&xl[(size_t)sb * 128 + c];
      float ta0 = xa.x + xrv.x; ta0 = (ta0 > 0.f ? ta0 : 0.2f * ta0) * at0;
      float ta1 = xa.y + xrv.y; ta1 = (ta1 > 0.f ? ta1 : 0.2f * ta1) * at1;
      float pa = ta0 + ta1;
      float tb0 = xb.x + xrv.x; tb0 = (tb0 > 0.f ? tb0 : 0.2f * tb0) * at0;
      float tb1 = xb.y + xrv.y; tb1 = (tb1 > 0.f ? tb1 : 0.2f * tb1) * at1;
      float pb = tb0 + tb1;
#pragma unroll
      for (int off = 16; off; off >>= 1) {
        pa += __shfl_xor(pa, off);
        pb += __shfl_xor(pb, off);
      }
      float mn = fmaxf(m, fmaxf(pa, pb));
      float sc = __expf(m - mn);
      float wa = __expf(pa - mn);
      float wb = __expf(pb - mn);
      acc0 = acc0 * sc + wa * xa.x + wb * xb.x;
      acc1 = acc1 * sc + wa * xa.y + wb * xb.y;
      l = l * sc + wa + wb;
      m = mn;
    }
    if (i < cnt) {
      int sa = __builtin_amdgcn_readfirstlane(__shfl(srcs, i));
      float2 xa = *(const float2*)&xl[(size_t)sa * 128 + c];
      float ta0 = xa.x + xrv.x; ta0 = (ta0 > 0.f ? ta0 : 0.2f * ta0) * at0;
      float ta1 = xa.y + xrv.y; ta1 = (ta1 > 0.f ? ta1 : 0.2f * ta1) * at1;
      float pa = ta0 + ta1;
#pragma unroll
      for (int off = 16; off; off >>= 1) pa += __shfl_xor(pa, off);
      float mn = fmaxf(m, pa);
      float sc = __expf(m - mn);
      float wa = __expf(pa - mn);
      acc0 = acc0 * sc + wa * xa.x;
      acc1 = acc1 * sc + wa * xa.y;
      l = l * sc + wa;
      m = mn;
    }
  }
  float inv = 1.f / (l + 1e-16f);
  float o0 = acc0 * inv + b1[c];
  float o1 = acc1 * inv + b1[c + 1];
  o0 = o0 > 0.f ? o0 : expm1f(o0);
  o1 = o1 > 0.f ? o1 : expm1f(o1);
  // fused layer-2 projection: al[j] = sum_c h_c*W2l[c][j], ar likewise
  float al0 = o0 * W2l[c * 3 + 0] + o1 * W2l[(c + 1) * 3 + 0];
  float al1 = o0 * W2l[c * 3 + 1] + o1 * W2l[(c + 1) * 3 + 1];
  float al2 = o0 * W2l[c * 3 + 2] + o1 * W2l[(c + 1) * 3 + 2];
  float ar0 = o0 * W2r[c * 3 + 0] + o1 * W2r[(c + 1) * 3 + 0];
  float ar1 = o0 * W2r[c * 3 + 1] + o1 * W2r[(c + 1) * 3 + 1];
  float ar2 = o0 * W2r[c * 3 + 2] + o1 * W2r[(c + 1) * 3 + 2];
#pragma unroll
  for (int off = 32; off; off >>= 1) {
    al0 += __shfl_xor(al0, off); al1 += __shfl_xor(al1, off);
    al2 += __shfl_xor(al2, off); ar0 += __shfl_xor(ar0, off);
    ar1 += __shfl_xor(ar1, off); ar2 += __shfl_xor(ar2, off);
  }
  if (lane == 0) {
    *(float4*)&xl2[node * 4] = make_float4(al0, al1, al2, 0.f);
    *(float4*)&xr2[node * 4] = make_float4(ar0, ar1, ar2, 0.f);
  }
}

// ---------------------------------------------------------------------------
// fused layer-2 edge phase + mean-pool. 16 lanes per node; each lane runs its
// own online softmax over a 16-stride slice of the node's in-edges, then the
// 16 partial (m,l,acc3) states merge via shfl. Pool pre-reduced in LDS.
__global__ __launch_bounds__(256) void k_fused2(const float* __restrict__ xl2,
                                                const float* __restrict__ xr2,
                                                const int* __restrict__ row_ptr,
                                                const int* __restrict__ csr_src,
                                                const float* __restrict__ att2,
                                                const float* __restrict__ b2,
                                                const int* __restrict__ batch,
                                                float* __restrict__ gsum,
                                                float* __restrict__ gcnt, int n) {
  __shared__ float ls[NGRAPH * 3];
  __shared__ float lc[NGRAPH];
  int t = threadIdx.x;
  for (int i = t; i < NGRAPH * 3; i += 256) ls[i] = 0.f;
  for (int i = t; i < NGRAPH; i += 256) lc[i] = 0.f;
  __syncthreads();

  int node = (blockIdx.x * 256 + t) >> 4;  // 16 nodes per block
  int lane = t & 15;
  if (node < n) {
    float4 xrv = *(const float4*)&xr2[node * 4];
    float c0 = att2[0], c1 = att2[1], c2 = att2[2];
    int s0 = row_ptr[node], s1 = row_ptr[node + 1];
    float m = -1e30f, l = 0.f, a0 = 0.f, a1 = 0.f, a2 = 0.f;
    for (int slot = s0 + lane; slot < s1; slot += 16) {
      int s = csr_src[slot];
      float4 xlv = *(const float4*)&xl2[s * 4];
      float t0 = xlv.x + xrv.x; t0 = t0 > 0.f ? t0 : 0.2f * t0;
      float t1 = xlv.y + xrv.y; t1 = t1 > 0.f ? t1 : 0.2f * t1;
      float t2 = xlv.z + xrv.z; t2 = t2 > 0.f ? t2 : 0.2f * t2;
      float p = t0 * c0 + t1 * c1 + t2 * c2;
      float mn = fmaxf(m, p);
      float sc = __expf(m - mn);
      float w  = __expf(p - mn);
      a0 = a0 * sc + w * xlv.x;
      a1 = a1 * sc + w * xlv.y;
      a2 = a2 * sc + w * xlv.z;
      l = l * sc + w;
      m = mn;
    }
#pragma unroll
    for (int off = 8; off; off >>= 1) {
      float m2 = __shfl_xor(m, off);
      float l2 = __shfl_xor(l, off);
      float b0 = __shfl_xor(a0, off);
      float b1v = __shfl_xor(a1, off);
      float b2v = __shfl_xor(a2, off);
      float mn = fmaxf(m, m2);
      float sA = __expf(m - mn);
      float sB = __expf(m2 - mn);
      a0 = a0 * sA + b0 * sB;
      a1 = a1 * sA + b1v * sB;
      a2 = a2 * sA + b2v * sB;
      l = l * sA + l2 * sB;
      m = mn;
    }
    if (lane == 0) {
      float inv = 1.f / (l + 1e-16f);
      float o0 = a0 * inv + b2[0];
      float o1 = a1 * inv + b2[1];
      float o2 = a2 * inv + b2[2];
      int b = batch[node];
      atomicAdd(&ls[b * 3 + 0], o0);
      atomicAdd(&ls[b * 3 + 1], o1);
      atomicAdd(&ls[b * 3 + 2], o2);
      atomicAdd(&lc[b], 1.f);
    }
  }
  __syncthreads();
  for (int i = t; i < NGRAPH * 3; i += 256)
    if (ls[i] != 0.f) atomicAdd(&gsum[i], ls[i]);
  for (int i = t; i < NGRAPH; i += 256)
    if (lc[i] != 0.f) atomicAdd(&gcnt[i], lc[i]);
}

// 1 block, 64 threads: per-graph mean + 2-layer MLP
__global__ __launch_bounds__(64) void k_mlp(const float* __restrict__ gsum,
                                            const float* __restrict__ gcnt,
                                            const float* __restrict__ Wr1,
                                            const float* __restrict__ br1,
                                            const float* __restrict__ Wr2,
                                            const float* __restrict__ br2,
                                            float* __restrict__ out) {
  int t = threadIdx.x;
  if (t >= NGRAPH) return;
  float cnt = fmaxf(gcnt[t], 1.f);
  float g0 = gsum[t * 3 + 0] / cnt;
  float g1 = gsum[t * 3 + 1] / cnt;
  float g2 = gsum[t * 3 + 2] / cnt;
  float o0 = br2[0], o1 = br2[1], o2 = br2[2];
  for (int j = 0; j < 64; ++j) {
    float hj = g0 * Wr1[j] + g1 * Wr1[64 + j] + g2 * Wr1[128 + j] + br1[j];
    hj = fmaxf(hj, 0.f);
    o0 = fmaf(hj, Wr2[j * 3 + 0], o0);
    o1 = fmaf(hj, Wr2[j * 3 + 1], o1);
    o2 = fmaf(hj, Wr2[j * 3 + 2], o2);
  }
  out[t * 3 + 0] = o0;
  out[t * 3 + 1] = o1;
  out[t * 3 + 2] = o2;
}

// ---------------------------------------------------------------------------
extern "C" void kernel_launch(void* const* d_in, const int* in_sizes, int n_in,
                              void* d_out, int out_size, void* d_ws, size_t ws_size,
                              hipStream_t stream) {
  const float* x    = (const float*)d_in[0];
  const int*   ei   = (const int*)d_in[1];
  const int*   batch= (const int*)d_in[2];
  const float* W1l  = (const float*)d_in[3];
  const float* W1r  = (const float*)d_in[4];
  const float* att1 = (const float*)d_in[5];
  const float* b1   = (const float*)d_in[6];
  const float* W2l  = (const float*)d_in[7];
  const float* W2r  = (const float*)d_in[8];
  const float* att2 = (const float*)d_in[9];
  const float* b2   = (const float*)d_in[10];
  const float* Wr1  = (const float*)d_in[11];
  const float* br1  = (const float*)d_in[12];
  const float* Wr2  = (const float*)d_in[13];
  const float* br2  = (const float*)d_in[14];
  float* out = (float*)d_out;

  const int N  = in_sizes[0] / 128;
  const int E  = in_sizes[1] / 2;
  const int Et = E + N;

  char* p = (char*)d_ws;
  auto alloc = [&](size_t bytes) -> char* {
    char* r = p;
    p += (bytes + 255) & ~(size_t)255;
    return r;
  };
  float*    xl1    = (float*)alloc((size_t)N * 128 * 4);
  float*    xr1    = (float*)alloc((size_t)N * 128 * 4);
  int*      row_ptr= (int*)alloc((size_t)(N + 1) * 4);
  int*      deg    = (int*)alloc((size_t)N * 4);
  int*      cursor = (int*)alloc((size_t)N * 4);
  int*      csr_src= (int*)alloc((size_t)Et * 4);
  float*    xl2    = (float*)alloc((size_t)N * 4 * 4);
  float*    xr2    = (float*)alloc((size_t)N * 4 * 4);
  float*    gsum   = (float*)alloc(NGRAPH * 3 * 4);
  float*    gcnt   = (float*)alloc(NGRAPH * 4);

  hipLaunchKernelGGL(k_init, dim3((N + 255) / 256), dim3(256), 0, stream,
                     deg, cursor, gsum, gcnt, N);
  hipLaunchKernelGGL(k_deg, dim3((Et + 255) / 256), dim3(256), 0, stream, ei, E, Et, deg);
  hipLaunchKernelGGL(k_scan, dim3(1), dim3(1024), 0, stream, deg, row_ptr, N);
  hipLaunchKernelGGL(k_fill, dim3((Et + 255) / 256), dim3(256), 0, stream,
                     ei, E, Et, row_ptr, cursor, csr_src);
  hipLaunchKernelGGL(k_gemm128, dim3((N + 15) / 16), dim3(256), 0, stream, x, W1l, xl1, N);
  hipLaunchKernelGGL(k_gemm128, dim3((N + 15) / 16), dim3(256), 0, stream, x, W1r, xr1, N);
  hipLaunchKernelGGL(k_fused1, dim3((N + 3) / 4), dim3(256), 0, stream,
                     xl1, xr1, row_ptr, csr_src, att1, b1, W2l, W2r, xl2, xr2, N);
  hipLaunchKernelGGL(k_fused2, dim3((N * 16 + 255) / 256), dim3(256), 0, stream,
                     xl2, xr2, row_ptr, csr_src, att2, b2, batch, gsum, gcnt, N);
  hipLaunchKernelGGL(k_mlp, dim3(1), dim3(64), 0, stream,
                     gsum, gcnt, Wr1, br1, Wr2, br2, out);
}

// Round 5
// 367.508 us; speedup vs baseline: 3.0707x; 1.0723x over previous
//
#include <hip/hip_runtime.h>

// ---------------------------------------------------------------------------
// GATv2 (2 layers) + mean-pool + MLP for MI355X. fp32 throughout.
// N=50000 nodes, E=800000 edges (+N self loops), IN=128, HID=64, HEADS=2,
// OUT=3, 64 graphs. Output: [64,3] float32.
// R1: k_agg2 pool atomic storm fixed (LDS pre-reduction). 1128 -> 803 us.
// R2: CSR + per-node online softmax; edge phases fused.   803 -> 515 us.
// R3: fused1 2-edge ILP + reg src cache + W2-proj fused.   515 -> 394 us.
// R4: fused1 implied 77 wave-instr/edge (VALUBusy 58%, no pipe saturated) ->
//     2 nodes/wave (32 lanes x float4 ch), 4-edge ILP per half, batched
//     online-softmax update, 4-step reduces, phantom-padded (clamped idx,
//     p=-1e30 -> w=0). Also: gemm128 y-merged (1 dispatch), k_init -> memset.
// ---------------------------------------------------------------------------

#define NGRAPH 64

__device__ __forceinline__ void edge_sd(const int* __restrict__ ei, int E, int e,
                                        int& s, int& d) {
  if (e < E) { s = ei[e]; d = ei[E + e]; }
  else       { s = e - E; d = s; }
}

// ---------------------------------------------------------------------------
__global__ void k_deg(const int* __restrict__ ei, int E, int Et, int* __restrict__ deg) {
  int e = blockIdx.x * blockDim.x + threadIdx.x;
  if (e >= Et) return;
  int s, d; edge_sd(ei, E, e, s, d);
  atomicAdd(&deg[d], 1);
}

// single block, 1024 threads: exclusive scan of deg -> row_ptr[0..n]
__global__ __launch_bounds__(1024) void k_scan(const int* __restrict__ deg,
                                               int* __restrict__ row_ptr, int n) {
  __shared__ int sdata[1024];
  int t = threadIdx.x;
  const int chunk = 52;
  int base = t * chunk;
  int end = min(base + chunk, n);
  int sum = 0;
  if (base + chunk <= n) {
#pragma unroll
    for (int i = 0; i < 13; ++i) {
      int4 d = *(const int4*)&deg[base + i * 4];
      sum += d.x + d.y + d.z + d.w;
    }
  } else {
    for (int i = base; i < end; ++i) sum += deg[i];
  }
  sdata[t] = sum;
  __syncthreads();
  for (int off = 1; off < 1024; off <<= 1) {
    int v = (t >= off) ? sdata[t - off] : 0;
    __syncthreads();
    sdata[t] += v;
    __syncthreads();
  }
  int run = sdata[t] - sum;  // exclusive prefix of this chunk
  if (base + chunk <= n) {
#pragma unroll
    for (int i = 0; i < 13; ++i) {
      int4 d = *(const int4*)&deg[base + i * 4];
      int4 r;
      r.x = run;       r.y = run + d.x;
      r.z = r.y + d.y; r.w = r.z + d.z;
      *(int4*)&row_ptr[base + i * 4] = r;
      run = r.w + d.w;
    }
  } else {
    for (int i = base; i < end; ++i) { row_ptr[i] = run; run += deg[i]; }
  }
  if (t == 1023) row_ptr[n] = sdata[1023];
}

__global__ void k_fill(const int* __restrict__ ei, int E, int Et,
                       const int* __restrict__ row_ptr, int* __restrict__ cursor,
                       int* __restrict__ csr_src) {
  int e = blockIdx.x * blockDim.x + threadIdx.x;
  if (e >= Et) return;
  int s, d; edge_sd(ei, E, e, s, d);
  int pos = atomicAdd(&cursor[d], 1);
  csr_src[row_ptr[d] + pos] = s;
}

// ---------------------------------------------------------------------------
// out[n,128] = x[n,128] @ W[128,128]. blockIdx.y selects (W1l->xl1)/(W1r->xr1).
__global__ __launch_bounds__(256) void k_gemm128(const float* __restrict__ x,
                                                 const float* __restrict__ Wl,
                                                 const float* __restrict__ Wr,
                                                 float* __restrict__ outl,
                                                 float* __restrict__ outr, int n) {
  __shared__ __align__(16) float Ws[128 * 128];
  __shared__ __align__(16) float xs[16][132];
  const float* W = blockIdx.y ? Wr : Wl;
  float* out = blockIdx.y ? outr : outl;
  int tid = threadIdx.x;
  const float4* W4 = (const float4*)W;
  float4* Ws4 = (float4*)Ws;
  for (int i = tid; i < 128 * 32; i += 256) Ws4[i] = W4[i];
  int r0 = blockIdx.x * 16;
  for (int i = tid; i < 16 * 32; i += 256) {
    int r = i >> 5, c4 = (i & 31) * 4;
    float4 v = make_float4(0.f, 0.f, 0.f, 0.f);
    if (r0 + r < n) v = *(const float4*)&x[(size_t)(r0 + r) * 128 + c4];
    xs[r][c4 + 0] = v.x; xs[r][c4 + 1] = v.y; xs[r][c4 + 2] = v.z; xs[r][c4 + 3] = v.w;
  }
  __syncthreads();
  int j = (tid & 31) * 4;
  int rp = tid >> 5;  // 0..7 -> rows rp, rp+8
  float a0x = 0.f, a0y = 0.f, a0z = 0.f, a0w = 0.f;
  float a1x = 0.f, a1y = 0.f, a1z = 0.f, a1w = 0.f;
#pragma unroll 8
  for (int k = 0; k < 128; ++k) {
    float4 w = *(const float4*)&Ws[k * 128 + j];
    float x0 = xs[rp][k], x1 = xs[rp + 8][k];
    a0x = fmaf(x0, w.x, a0x); a0y = fmaf(x0, w.y, a0y);
    a0z = fmaf(x0, w.z, a0z); a0w = fmaf(x0, w.w, a0w);
    a1x = fmaf(x1, w.x, a1x); a1y = fmaf(x1, w.y, a1y);
    a1z = fmaf(x1, w.z, a1z); a1w = fmaf(x1, w.w, a1w);
  }
  int r = r0 + rp;
  if (r < n) *(float4*)&out[(size_t)r * 128 + j] = make_float4(a0x, a0y, a0z, a0w);
  r = r0 + rp + 8;
  if (r < n) *(float4*)&out[(size_t)r * 128 + j] = make_float4(a1x, a1y, a1z, a1w);
}

// ---------------------------------------------------------------------------
// R4: fused layer-1 edge phase + layer-2 input projection.
// TWO nodes per wave: lanes 0-31 = node A, 32-63 = node B. Each lane holds 4
// channels (float4); sub<16 = head 0, sub>=16 = head 1. 4 edges per half per
// iteration (4 gathers in flight), 4-step shfl reduce per logit, one batched
// online-softmax update per 4 edges. Out-of-range edges: index clamped to the
// last real edge (L1-hot row) and logit forced to -1e30 -> weight exactly 0.
// Epilogue: ELU then h @ W2l / h @ W2r via 6 reductions over 32 lanes.
__global__ __launch_bounds__(256) void k_fused1(const float* __restrict__ xl,
                                                const float* __restrict__ xr,
                                                const int* __restrict__ row_ptr,
                                                const int* __restrict__ csr_src,
                                                const float* __restrict__ att1,
                                                const float* __restrict__ b1,
                                                const float* __restrict__ W2l,
                                                const float* __restrict__ W2r,
                                                float* __restrict__ xl2,
                                                float* __restrict__ xr2, int n) {
  int wid  = (blockIdx.x * 256 + threadIdx.x) >> 6;
  int lane = threadIdx.x & 63;
  int sub  = lane & 31;
  int node = wid * 2 + (lane >> 5);
  bool valid = node < n;
  int nc = valid ? node : 0;
  int ch = sub * 4;
  float4 xrv = *(const float4*)&xr[(size_t)nc * 128 + ch];
  float4 atv = *(const float4*)&att1[ch];
  int s0 = row_ptr[nc];
  int deg = valid ? (row_ptr[nc + 1] - s0) : 1;  // every node has self-loop
  int dm1 = deg - 1;
  int maxdeg = max(deg, __shfl_xor(deg, 32));  // wave-uniform loop bound

  float m = -1e30f, l = 0.f;
  float4 acc = make_float4(0.f, 0.f, 0.f, 0.f);

  // prefetch first 4 src indices (clamped; broadcast within each half)
  int sA = csr_src[s0 + min(0, dm1)];
  int sB = csr_src[s0 + min(1, dm1)];
  int sC = csr_src[s0 + min(2, dm1)];
  int sD = csr_src[s0 + min(3, dm1)];

  for (int e = 0; e < maxdeg; e += 4) {
    float4 xa = *(const float4*)&xl[(size_t)sA * 128 + ch];
    float4 xb = *(const float4*)&xl[(size_t)sB * 128 + ch];
    float4 xc = *(const float4*)&xl[(size_t)sC * 128 + ch];
    float4 xd = *(const float4*)&xl[(size_t)sD * 128 + ch];
    int e4 = e + 4;
    sA = csr_src[s0 + min(e4 + 0, dm1)];
    sB = csr_src[s0 + min(e4 + 1, dm1)];
    sC = csr_src[s0 + min(e4 + 2, dm1)];
    sD = csr_src[s0 + min(e4 + 3, dm1)];

    float t0, t1, t2, t3;
#define LOGIT(p, v)                                                     \
    t0 = v.x + xrv.x; t0 = fmaxf(t0, 0.2f * t0);                        \
    t1 = v.y + xrv.y; t1 = fmaxf(t1, 0.2f * t1);                        \
    t2 = v.z + xrv.z; t2 = fmaxf(t2, 0.2f * t2);                        \
    t3 = v.w + xrv.w; t3 = fmaxf(t3, 0.2f * t3);                        \
    p = fmaf(t3, atv.w, fmaf(t2, atv.z, fmaf(t1, atv.y, t0 * atv.x)));
    float pa, pb, pc, pd;
    LOGIT(pa, xa) LOGIT(pb, xb) LOGIT(pc, xc) LOGIT(pd, xd)
#undef LOGIT
#pragma unroll
    for (int off = 1; off < 16; off <<= 1) {  // reduce within 16-lane head group
      pa += __shfl_xor(pa, off);
      pb += __shfl_xor(pb, off);
      pc += __shfl_xor(pc, off);
      pd += __shfl_xor(pd, off);
    }
    pa = (e + 0 < deg) ? pa : -1e30f;
    pb = (e + 1 < deg) ? pb : -1e30f;
    pc = (e + 2 < deg) ? pc : -1e30f;
    pd = (e + 3 < deg) ? pd : -1e30f;
    float mn = fmaxf(m, fmaxf(fmaxf(pa, pb), fmaxf(pc, pd)));
    float sc = __expf(m - mn);
    float wa = __expf(pa - mn);
    float wb = __expf(pb - mn);
    float wc = __expf(pc - mn);
    float wd = __expf(pd - mn);
    acc.x = fmaf(wd, xd.x, fmaf(wc, xc.x, fmaf(wb, xb.x, fmaf(wa, xa.x, acc.x * sc))));
    acc.y = fmaf(wd, xd.y, fmaf(wc, xc.y, fmaf(wb, xb.y, fmaf(wa, xa.y, acc.y * sc))));
    acc.z = fmaf(wd, xd.z, fmaf(wc, xc.z, fmaf(wb, xb.z, fmaf(wa, xa.z, acc.z * sc))));
    acc.w = fmaf(wd, xd.w, fmaf(wc, xc.w, fmaf(wb, xb.w, fmaf(wa, xa.w, acc.w * sc))));
    l = fmaf(l, sc, wa + wb + wc + wd);
    m = mn;
  }

  float inv = 1.f / (l + 1e-16f);
  float4 b1v = *(const float4*)&b1[ch];
  float4 h;
  h.x = acc.x * inv + b1v.x; h.x = h.x > 0.f ? h.x : expm1f(h.x);
  h.y = acc.y * inv + b1v.y; h.y = h.y > 0.f ? h.y : expm1f(h.y);
  h.z = acc.z * inv + b1v.z; h.z = h.z > 0.f ? h.z : expm1f(h.z);
  h.w = acc.w * inv + b1v.w; h.w = h.w > 0.f ? h.w : expm1f(h.w);

  // fused layer-2 projection: rows ch..ch+3 of W2l/W2r = 12 contiguous floats
  float4 u0 = *(const float4*)&W2l[ch * 3 + 0];
  float4 u1 = *(const float4*)&W2l[ch * 3 + 4];
  float4 u2 = *(const float4*)&W2l[ch * 3 + 8];
  float al0 = fmaf(h.w, u2.y, fmaf(h.z, u1.z, fmaf(h.y, u0.w, h.x * u0.x)));
  float al1 = fmaf(h.w, u2.z, fmaf(h.z, u1.w, fmaf(h.y, u1.x, h.x * u0.y)));
  float al2 = fmaf(h.w, u2.w, fmaf(h.z, u2.x, fmaf(h.y, u1.y, h.x * u0.z)));
  float4 v0 = *(const float4*)&W2r[ch * 3 + 0];
  float4 v1 = *(const float4*)&W2r[ch * 3 + 4];
  float4 v2 = *(const float4*)&W2r[ch * 3 + 8];
  float ar0 = fmaf(h.w, v2.y, fmaf(h.z, v1.z, fmaf(h.y, v0.w, h.x * v0.x)));
  float ar1 = fmaf(h.w, v2.z, fmaf(h.z, v1.w, fmaf(h.y, v1.x, h.x * v0.y)));
  float ar2 = fmaf(h.w, v2.w, fmaf(h.z, v2.x, fmaf(h.y, v1.y, h.x * v0.z)));
#pragma unroll
  for (int off = 1; off < 32; off <<= 1) {  // reduce over the half's 32 lanes
    al0 += __shfl_xor(al0, off); al1 += __shfl_xor(al1, off);
    al2 += __shfl_xor(al2, off); ar0 += __shfl_xor(ar0, off);
    ar1 += __shfl_xor(ar1, off); ar2 += __shfl_xor(ar2, off);
  }
  if (valid && sub == 0) {
    *(float4*)&xl2[node * 4] = make_float4(al0, al1, al2, 0.f);
    *(float4*)&xr2[node * 4] = make_float4(ar0, ar1, ar2, 0.f);
  }
}

// ---------------------------------------------------------------------------
// fused layer-2 edge phase + mean-pool. 16 lanes per node; each lane runs its
// own online softmax over a 16-stride slice of the node's in-edges, then the
// 16 partial (m,l,acc3) states merge via shfl. Pool pre-reduced in LDS.
__global__ __launch_bounds__(256) void k_fused2(const float* __restrict__ xl2,
                                                const float* __restrict__ xr2,
                                                const int* __restrict__ row_ptr,
                                                const int* __restrict__ csr_src,
                                                const float* __restrict__ att2,
                                                const float* __restrict__ b2,
                                                const int* __restrict__ batch,
                                                float* __restrict__ gsum,
                                                float* __restrict__ gcnt, int n) {
  __shared__ float ls[NGRAPH * 3];
  __shared__ float lc[NGRAPH];
  int t = threadIdx.x;
  for (int i = t; i < NGRAPH * 3; i += 256) ls[i] = 0.f;
  for (int i = t; i < NGRAPH; i += 256) lc[i] = 0.f;
  __syncthreads();

  int node = (blockIdx.x * 256 + t) >> 4;  // 16 nodes per block
  int lane = t & 15;
  if (node < n) {
    float4 xrv = *(const float4*)&xr2[node * 4];
    float c0 = att2[0], c1 = att2[1], c2 = att2[2];
    int s0 = row_ptr[node], s1 = row_ptr[node + 1];
    float m = -1e30f, l = 0.f, a0 = 0.f, a1 = 0.f, a2 = 0.f;
    for (int slot = s0 + lane; slot < s1; slot += 16) {
      int s = csr_src[slot];
      float4 xlv = *(const float4*)&xl2[s * 4];
      float t0 = xlv.x + xrv.x; t0 = fmaxf(t0, 0.2f * t0);
      float t1 = xlv.y + xrv.y; t1 = fmaxf(t1, 0.2f * t1);
      float t2 = xlv.z + xrv.z; t2 = fmaxf(t2, 0.2f * t2);
      float p = t0 * c0 + t1 * c1 + t2 * c2;
      float mn = fmaxf(m, p);
      float sc = __expf(m - mn);
      float w  = __expf(p - mn);
      a0 = a0 * sc + w * xlv.x;
      a1 = a1 * sc + w * xlv.y;
      a2 = a2 * sc + w * xlv.z;
      l = l * sc + w;
      m = mn;
    }
#pragma unroll
    for (int off = 8; off; off >>= 1) {
      float m2 = __shfl_xor(m, off);
      float l2 = __shfl_xor(l, off);
      float b0 = __shfl_xor(a0, off);
      float b1v = __shfl_xor(a1, off);
      float b2v = __shfl_xor(a2, off);
      float mn = fmaxf(m, m2);
      float sA = __expf(m - mn);
      float sB = __expf(m2 - mn);
      a0 = a0 * sA + b0 * sB;
      a1 = a1 * sA + b1v * sB;
      a2 = a2 * sA + b2v * sB;
      l = l * sA + l2 * sB;
      m = mn;
    }
    if (lane == 0) {
      float inv = 1.f / (l + 1e-16f);
      float o0 = a0 * inv + b2[0];
      float o1 = a1 * inv + b2[1];
      float o2 = a2 * inv + b2[2];
      int b = batch[node];
      atomicAdd(&ls[b * 3 + 0], o0);
      atomicAdd(&ls[b * 3 + 1], o1);
      atomicAdd(&ls[b * 3 + 2], o2);
      atomicAdd(&lc[b], 1.f);
    }
  }
  __syncthreads();
  for (int i = t; i < NGRAPH * 3; i += 256)
    if (ls[i] != 0.f) atomicAdd(&gsum[i], ls[i]);
  for (int i = t; i < NGRAPH; i += 256)
    if (lc[i] != 0.f) atomicAdd(&gcnt[i], lc[i]);
}

// 1 block, 64 threads: per-graph mean + 2-layer MLP
__global__ __launch_bounds__(64) void k_mlp(const float* __restrict__ gsum,
                                            const float* __restrict__ gcnt,
                                            const float* __restrict__ Wr1,
                                            const float* __restrict__ br1,
                                            const float* __restrict__ Wr2,
                                            const float* __restrict__ br2,
                                            float* __restrict__ out) {
  int t = threadIdx.x;
  if (t >= NGRAPH) return;
  float cnt = fmaxf(gcnt[t], 1.f);
  float g0 = gsum[t * 3 + 0] / cnt;
  float g1 = gsum[t * 3 + 1] / cnt;
  float g2 = gsum[t * 3 + 2] / cnt;
  float o0 = br2[0], o1 = br2[1], o2 = br2[2];
  for (int j = 0; j < 64; ++j) {
    float hj = g0 * Wr1[j] + g1 * Wr1[64 + j] + g2 * Wr1[128 + j] + br1[j];
    hj = fmaxf(hj, 0.f);
    o0 = fmaf(hj, Wr2[j * 3 + 0], o0);
    o1 = fmaf(hj, Wr2[j * 3 + 1], o1);
    o2 = fmaf(hj, Wr2[j * 3 + 2], o2);
  }
  out[t * 3 + 0] = o0;
  out[t * 3 + 1] = o1;
  out[t * 3 + 2] = o2;
}

// ---------------------------------------------------------------------------
extern "C" void kernel_launch(void* const* d_in, const int* in_sizes, int n_in,
                              void* d_out, int out_size, void* d_ws, size_t ws_size,
                              hipStream_t stream) {
  const float* x    = (const float*)d_in[0];
  const int*   ei   = (const int*)d_in[1];
  const int*   batch= (const int*)d_in[2];
  const float* W1l  = (const float*)d_in[3];
  const float* W1r  = (const float*)d_in[4];
  const float* att1 = (const float*)d_in[5];
  const float* b1   = (const float*)d_in[6];
  const float* W2l  = (const float*)d_in[7];
  const float* W2r  = (const float*)d_in[8];
  const float* att2 = (const float*)d_in[9];
  const float* b2   = (const float*)d_in[10];
  const float* Wr1  = (const float*)d_in[11];
  const float* br1  = (const float*)d_in[12];
  const float* Wr2  = (const float*)d_in[13];
  const float* br2  = (const float*)d_in[14];
  float* out = (float*)d_out;

  const int N  = in_sizes[0] / 128;
  const int E  = in_sizes[1] / 2;
  const int Et = E + N;

  char* p = (char*)d_ws;
  auto alloc = [&](size_t bytes) -> char* {
    char* r = p;
    p += (bytes + 255) & ~(size_t)255;
    return r;
  };
  float*    xl1    = (float*)alloc((size_t)N * 128 * 4);
  float*    xr1    = (float*)alloc((size_t)N * 128 * 4);
  int*      row_ptr= (int*)alloc((size_t)(N + 1) * 4);
  int*      csr_src= (int*)alloc((size_t)Et * 4);
  // zero-init group (one memset): deg | cursor | gsum | gcnt
  char*     z0     = p;
  int*      deg    = (int*)alloc((size_t)N * 4);
  int*      cursor = (int*)alloc((size_t)N * 4);
  float*    gsum   = (float*)alloc(NGRAPH * 3 * 4);
  float*    gcnt   = (float*)alloc(NGRAPH * 4);
  size_t    zbytes = (size_t)(p - z0);
  float*    xl2    = (float*)alloc((size_t)N * 4 * 4);
  float*    xr2    = (float*)alloc((size_t)N * 4 * 4);

  hipMemsetAsync(z0, 0, zbytes, stream);
  hipLaunchKernelGGL(k_deg, dim3((Et + 255) / 256), dim3(256), 0, stream, ei, E, Et, deg);
  hipLaunchKernelGGL(k_scan, dim3(1), dim3(1024), 0, stream, deg, row_ptr, N);
  hipLaunchKernelGGL(k_fill, dim3((Et + 255) / 256), dim3(256), 0, stream,
                     ei, E, Et, row_ptr, cursor, csr_src);
  hipLaunchKernelGGL(k_gemm128, dim3((N + 15) / 16, 2), dim3(256), 0, stream,
                     x, W1l, W1r, xl1, xr1, N);
  int waves1 = (N + 1) / 2;
  hipLaunchKernelGGL(k_fused1, dim3((waves1 * 64 + 255) / 256), dim3(256), 0, stream,
                     xl1, xr1, row_ptr, csr_src, att1, b1, W2l, W2r, xl2, xr2, N);
  hipLaunchKernelGGL(k_fused2, dim3((N * 16 + 255) / 256), dim3(256), 0, stream,
                     xl2, xr2, row_ptr, csr_src, att2, b2, batch, gsum, gcnt, N);
  hipLaunchKernelGGL(k_mlp, dim3(1), dim3(64), 0, stream,
                     gsum, gcnt, Wr1, br1, Wr2, br2, out);
}

// Round 6
// 342.675 us; speedup vs baseline: 3.2932x; 1.0725x over previous
//
#include <hip/hip_runtime.h>

// ---------------------------------------------------------------------------
// GATv2 (2 layers) + mean-pool + MLP for MI355X. fp32 throughout.
// N=50000 nodes, E=800000 edges (+N self loops), IN=128, HID=64, HEADS=2,
// OUT=3, 64 graphs. Output: [64,3] float32.
// R1: k_agg2 pool atomic storm fixed (LDS pre-reduction). 1128 -> 803 us.
// R2: CSR + per-node online softmax; edge phases fused.   803 -> 515 us.
// R3: fused1 2-edge ILP + reg src cache + W2-proj fused.   515 -> 394 us.
// R4: fused1 2 nodes/wave + 4-edge ILP + batched softmax.  394 -> 368 us.
// R5: k_gemm128 was top (98us): 72KB LDS -> 20% occupancy, 8 FMA per 3 LDS
//     reads. Now: 128x128 tile, BK=16, 8x8 micro-tile/thread (64 FMA per
//     4 ds_read_b128), LDS 16.5KB, 782 blocks fully resident.
// ---------------------------------------------------------------------------

#define NGRAPH 64

__device__ __forceinline__ void edge_sd(const int* __restrict__ ei, int E, int e,
                                        int& s, int& d) {
  if (e < E) { s = ei[e]; d = ei[E + e]; }
  else       { s = e - E; d = s; }
}

// ---------------------------------------------------------------------------
__global__ void k_deg(const int* __restrict__ ei, int E, int Et, int* __restrict__ deg) {
  int e = blockIdx.x * blockDim.x + threadIdx.x;
  if (e >= Et) return;
  int s, d; edge_sd(ei, E, e, s, d);
  atomicAdd(&deg[d], 1);
}

// single block, 1024 threads: exclusive scan of deg -> row_ptr[0..n]
__global__ __launch_bounds__(1024) void k_scan(const int* __restrict__ deg,
                                               int* __restrict__ row_ptr, int n) {
  __shared__ int sdata[1024];
  int t = threadIdx.x;
  const int chunk = 52;
  int base = t * chunk;
  int end = min(base + chunk, n);
  int sum = 0;
  if (base + chunk <= n) {
#pragma unroll
    for (int i = 0; i < 13; ++i) {
      int4 d = *(const int4*)&deg[base + i * 4];
      sum += d.x + d.y + d.z + d.w;
    }
  } else {
    for (int i = base; i < end; ++i) sum += deg[i];
  }
  sdata[t] = sum;
  __syncthreads();
  for (int off = 1; off < 1024; off <<= 1) {
    int v = (t >= off) ? sdata[t - off] : 0;
    __syncthreads();
    sdata[t] += v;
    __syncthreads();
  }
  int run = sdata[t] - sum;  // exclusive prefix of this chunk
  if (base + chunk <= n) {
#pragma unroll
    for (int i = 0; i < 13; ++i) {
      int4 d = *(const int4*)&deg[base + i * 4];
      int4 r;
      r.x = run;       r.y = run + d.x;
      r.z = r.y + d.y; r.w = r.z + d.z;
      *(int4*)&row_ptr[base + i * 4] = r;
      run = r.w + d.w;
    }
  } else {
    for (int i = base; i < end; ++i) { row_ptr[i] = run; run += deg[i]; }
  }
  if (t == 1023) row_ptr[n] = sdata[1023];
}

__global__ void k_fill(const int* __restrict__ ei, int E, int Et,
                       const int* __restrict__ row_ptr, int* __restrict__ cursor,
                       int* __restrict__ csr_src) {
  int e = blockIdx.x * blockDim.x + threadIdx.x;
  if (e >= Et) return;
  int s, d; edge_sd(ei, E, e, s, d);
  int pos = atomicAdd(&cursor[d], 1);
  csr_src[row_ptr[d] + pos] = s;
}

// ---------------------------------------------------------------------------
// R5: out[n,128] = x[n,128] @ W[128,128], blockIdx.y selects Wl/Wr.
// 128x128 block tile, BK=16, 256 threads, 8x8 register micro-tile.
__global__ __launch_bounds__(256) void k_gemm128(const float* __restrict__ x,
                                                 const float* __restrict__ Wl,
                                                 const float* __restrict__ Wr,
                                                 float* __restrict__ outl,
                                                 float* __restrict__ outr, int n) {
  __shared__ __align__(16) float xs[16][132];  // x tile transposed: [k][row]
  __shared__ __align__(16) float ws[16][132];  // W tile: [k][col]
  const float* W = blockIdx.y ? Wr : Wl;
  float* out = blockIdx.y ? outr : outl;
  int t = threadIdx.x;
  int tx = t & 15, ty = t >> 4;
  int r0 = blockIdx.x * 128;
  float acc[8][8] = {};

  int lr = t >> 2;           // staging: row within pass (0..63)
  int lk = (t & 3) * 4;      // k-quad
  int wk = t >> 5;           // W staging: k row (0..7)
  int wc = (t & 31) * 4;     // col quad

  for (int k0 = 0; k0 < 128; k0 += 16) {
    __syncthreads();
#pragma unroll
    for (int pass = 0; pass < 2; ++pass) {
      int r = lr + pass * 64;
      int gr = r0 + r;
      float4 v = make_float4(0.f, 0.f, 0.f, 0.f);
      if (gr < n) v = *(const float4*)&x[(size_t)gr * 128 + k0 + lk];
      xs[lk + 0][r] = v.x;
      xs[lk + 1][r] = v.y;
      xs[lk + 2][r] = v.z;
      xs[lk + 3][r] = v.w;
    }
#pragma unroll
    for (int pass = 0; pass < 2; ++pass) {
      int k = wk + pass * 8;
      *(float4*)&ws[k][wc] = *(const float4*)&W[(size_t)(k0 + k) * 128 + wc];
    }
    __syncthreads();
#pragma unroll
    for (int k = 0; k < 16; ++k) {
      float4 a0 = *(const float4*)&xs[k][ty * 8];
      float4 a1 = *(const float4*)&xs[k][ty * 8 + 4];
      float4 b0 = *(const float4*)&ws[k][tx * 8];
      float4 b1 = *(const float4*)&ws[k][tx * 8 + 4];
      float a[8] = {a0.x, a0.y, a0.z, a0.w, a1.x, a1.y, a1.z, a1.w};
      float b[8] = {b0.x, b0.y, b0.z, b0.w, b1.x, b1.y, b1.z, b1.w};
#pragma unroll
      for (int i = 0; i < 8; ++i)
#pragma unroll
        for (int j = 0; j < 8; ++j)
          acc[i][j] = fmaf(a[i], b[j], acc[i][j]);
    }
  }
#pragma unroll
  for (int i = 0; i < 8; ++i) {
    int gr = r0 + ty * 8 + i;
    if (gr < n) {
      *(float4*)&out[(size_t)gr * 128 + tx * 8] =
          make_float4(acc[i][0], acc[i][1], acc[i][2], acc[i][3]);
      *(float4*)&out[(size_t)gr * 128 + tx * 8 + 4] =
          make_float4(acc[i][4], acc[i][5], acc[i][6], acc[i][7]);
    }
  }
}

// ---------------------------------------------------------------------------
// R4: fused layer-1 edge phase + layer-2 input projection.
// TWO nodes per wave: lanes 0-31 = node A, 32-63 = node B. Each lane holds 4
// channels (float4); sub<16 = head 0, sub>=16 = head 1. 4 edges per half per
// iteration, 4-step shfl reduce per logit, one batched online-softmax update
// per 4 edges. Out-of-range edges: index clamped (L1-hot), logit -1e30 -> w=0.
__global__ __launch_bounds__(256) void k_fused1(const float* __restrict__ xl,
                                                const float* __restrict__ xr,
                                                const int* __restrict__ row_ptr,
                                                const int* __restrict__ csr_src,
                                                const float* __restrict__ att1,
                                                const float* __restrict__ b1,
                                                const float* __restrict__ W2l,
                                                const float* __restrict__ W2r,
                                                float* __restrict__ xl2,
                                                float* __restrict__ xr2, int n) {
  int wid  = (blockIdx.x * 256 + threadIdx.x) >> 6;
  int lane = threadIdx.x & 63;
  int sub  = lane & 31;
  int node = wid * 2 + (lane >> 5);
  bool valid = node < n;
  int nc = valid ? node : 0;
  int ch = sub * 4;
  float4 xrv = *(const float4*)&xr[(size_t)nc * 128 + ch];
  float4 atv = *(const float4*)&att1[ch];
  int s0 = row_ptr[nc];
  int deg = valid ? (row_ptr[nc + 1] - s0) : 1;  // every node has self-loop
  int dm1 = deg - 1;
  int maxdeg = max(deg, __shfl_xor(deg, 32));  // wave-uniform loop bound

  float m = -1e30f, l = 0.f;
  float4 acc = make_float4(0.f, 0.f, 0.f, 0.f);

  int sA = csr_src[s0 + min(0, dm1)];
  int sB = csr_src[s0 + min(1, dm1)];
  int sC = csr_src[s0 + min(2, dm1)];
  int sD = csr_src[s0 + min(3, dm1)];

  for (int e = 0; e < maxdeg; e += 4) {
    float4 xa = *(const float4*)&xl[(size_t)sA * 128 + ch];
    float4 xb = *(const float4*)&xl[(size_t)sB * 128 + ch];
    float4 xc = *(const float4*)&xl[(size_t)sC * 128 + ch];
    float4 xd = *(const float4*)&xl[(size_t)sD * 128 + ch];
    int e4 = e + 4;
    sA = csr_src[s0 + min(e4 + 0, dm1)];
    sB = csr_src[s0 + min(e4 + 1, dm1)];
    sC = csr_src[s0 + min(e4 + 2, dm1)];
    sD = csr_src[s0 + min(e4 + 3, dm1)];

    float t0, t1, t2, t3;
#define LOGIT(p, v)                                                     \
    t0 = v.x + xrv.x; t0 = fmaxf(t0, 0.2f * t0);                        \
    t1 = v.y + xrv.y; t1 = fmaxf(t1, 0.2f * t1);                        \
    t2 = v.z + xrv.z; t2 = fmaxf(t2, 0.2f * t2);                        \
    t3 = v.w + xrv.w; t3 = fmaxf(t3, 0.2f * t3);                        \
    p = fmaf(t3, atv.w, fmaf(t2, atv.z, fmaf(t1, atv.y, t0 * atv.x)));
    float pa, pb, pc, pd;
    LOGIT(pa, xa) LOGIT(pb, xb) LOGIT(pc, xc) LOGIT(pd, xd)
#undef LOGIT
#pragma unroll
    for (int off = 1; off < 16; off <<= 1) {
      pa += __shfl_xor(pa, off);
      pb += __shfl_xor(pb, off);
      pc += __shfl_xor(pc, off);
      pd += __shfl_xor(pd, off);
    }
    pa = (e + 0 < deg) ? pa : -1e30f;
    pb = (e + 1 < deg) ? pb : -1e30f;
    pc = (e + 2 < deg) ? pc : -1e30f;
    pd = (e + 3 < deg) ? pd : -1e30f;
    float mn = fmaxf(m, fmaxf(fmaxf(pa, pb), fmaxf(pc, pd)));
    float sc = __expf(m - mn);
    float wa = __expf(pa - mn);
    float wb = __expf(pb - mn);
    float wc = __expf(pc - mn);
    float wd = __expf(pd - mn);
    acc.x = fmaf(wd, xd.x, fmaf(wc, xc.x, fmaf(wb, xb.x, fmaf(wa, xa.x, acc.x * sc))));
    acc.y = fmaf(wd, xd.y, fmaf(wc, xc.y, fmaf(wb, xb.y, fmaf(wa, xa.y, acc.y * sc))));
    acc.z = fmaf(wd, xd.z, fmaf(wc, xc.z, fmaf(wb, xb.z, fmaf(wa, xa.z, acc.z * sc))));
    acc.w = fmaf(wd, xd.w, fmaf(wc, xc.w, fmaf(wb, xb.w, fmaf(wa, xa.w, acc.w * sc))));
    l = fmaf(l, sc, wa + wb + wc + wd);
    m = mn;
  }

  float inv = 1.f / (l + 1e-16f);
  float4 b1v = *(const float4*)&b1[ch];
  float4 h;
  h.x = acc.x * inv + b1v.x; h.x = h.x > 0.f ? h.x : expm1f(h.x);
  h.y = acc.y * inv + b1v.y; h.y = h.y > 0.f ? h.y : expm1f(h.y);
  h.z = acc.z * inv + b1v.z; h.z = h.z > 0.f ? h.z : expm1f(h.z);
  h.w = acc.w * inv + b1v.w; h.w = h.w > 0.f ? h.w : expm1f(h.w);

  float4 u0 = *(const float4*)&W2l[ch * 3 + 0];
  float4 u1 = *(const float4*)&W2l[ch * 3 + 4];
  float4 u2 = *(const float4*)&W2l[ch * 3 + 8];
  float al0 = fmaf(h.w, u2.y, fmaf(h.z, u1.z, fmaf(h.y, u0.w, h.x * u0.x)));
  float al1 = fmaf(h.w, u2.z, fmaf(h.z, u1.w, fmaf(h.y, u1.x, h.x * u0.y)));
  float al2 = fmaf(h.w, u2.w, fmaf(h.z, u2.x, fmaf(h.y, u1.y, h.x * u0.z)));
  float4 v0 = *(const float4*)&W2r[ch * 3 + 0];
  float4 v1 = *(const float4*)&W2r[ch * 3 + 4];
  float4 v2 = *(const float4*)&W2r[ch * 3 + 8];
  float ar0 = fmaf(h.w, v2.y, fmaf(h.z, v1.z, fmaf(h.y, v0.w, h.x * v0.x)));
  float ar1 = fmaf(h.w, v2.z, fmaf(h.z, v1.w, fmaf(h.y, v1.x, h.x * v0.y)));
  float ar2 = fmaf(h.w, v2.w, fmaf(h.z, v2.x, fmaf(h.y, v1.y, h.x * v0.z)));
#pragma unroll
  for (int off = 1; off < 32; off <<= 1) {
    al0 += __shfl_xor(al0, off); al1 += __shfl_xor(al1, off);
    al2 += __shfl_xor(al2, off); ar0 += __shfl_xor(ar0, off);
    ar1 += __shfl_xor(ar1, off); ar2 += __shfl_xor(ar2, off);
  }
  if (valid && sub == 0) {
    *(float4*)&xl2[node * 4] = make_float4(al0, al1, al2, 0.f);
    *(float4*)&xr2[node * 4] = make_float4(ar0, ar1, ar2, 0.f);
  }
}

// ---------------------------------------------------------------------------
// fused layer-2 edge phase + mean-pool. 16 lanes per node; per-lane online
// softmax over a 16-stride slice, shfl state merge. Pool pre-reduced in LDS.
__global__ __launch_bounds__(256) void k_fused2(const float* __restrict__ xl2,
                                                const float* __restrict__ xr2,
                                                const int* __restrict__ row_ptr,
                                                const int* __restrict__ csr_src,
                                                const float* __restrict__ att2,
                                                const float* __restrict__ b2,
                                                const int* __restrict__ batch,
                                                float* __restrict__ gsum,
                                                float* __restrict__ gcnt, int n) {
  __shared__ float ls[NGRAPH * 3];
  __shared__ float lc[NGRAPH];
  int t = threadIdx.x;
  for (int i = t; i < NGRAPH * 3; i += 256) ls[i] = 0.f;
  for (int i = t; i < NGRAPH; i += 256) lc[i] = 0.f;
  __syncthreads();

  int node = (blockIdx.x * 256 + t) >> 4;  // 16 nodes per block
  int lane = t & 15;
  if (node < n) {
    float4 xrv = *(const float4*)&xr2[node * 4];
    float c0 = att2[0], c1 = att2[1], c2 = att2[2];
    int s0 = row_ptr[node], s1 = row_ptr[node + 1];
    float m = -1e30f, l = 0.f, a0 = 0.f, a1 = 0.f, a2 = 0.f;
    for (int slot = s0 + lane; slot < s1; slot += 16) {
      int s = csr_src[slot];
      float4 xlv = *(const float4*)&xl2[s * 4];
      float t0 = xlv.x + xrv.x; t0 = fmaxf(t0, 0.2f * t0);
      float t1 = xlv.y + xrv.y; t1 = fmaxf(t1, 0.2f * t1);
      float t2 = xlv.z + xrv.z; t2 = fmaxf(t2, 0.2f * t2);
      float p = t0 * c0 + t1 * c1 + t2 * c2;
      float mn = fmaxf(m, p);
      float sc = __expf(m - mn);
      float w  = __expf(p - mn);
      a0 = a0 * sc + w * xlv.x;
      a1 = a1 * sc + w * xlv.y;
      a2 = a2 * sc + w * xlv.z;
      l = l * sc + w;
      m = mn;
    }
#pragma unroll
    for (int off = 8; off; off >>= 1) {
      float m2 = __shfl_xor(m, off);
      float l2 = __shfl_xor(l, off);
      float b0 = __shfl_xor(a0, off);
      float b1v = __shfl_xor(a1, off);
      float b2v = __shfl_xor(a2, off);
      float mn = fmaxf(m, m2);
      float sA = __expf(m - mn);
      float sB = __expf(m2 - mn);
      a0 = a0 * sA + b0 * sB;
      a1 = a1 * sA + b1v * sB;
      a2 = a2 * sA + b2v * sB;
      l = l * sA + l2 * sB;
      m = mn;
    }
    if (lane == 0) {
      float inv = 1.f / (l + 1e-16f);
      float o0 = a0 * inv + b2[0];
      float o1 = a1 * inv + b2[1];
      float o2 = a2 * inv + b2[2];
      int b = batch[node];
      atomicAdd(&ls[b * 3 + 0], o0);
      atomicAdd(&ls[b * 3 + 1], o1);
      atomicAdd(&ls[b * 3 + 2], o2);
      atomicAdd(&lc[b], 1.f);
    }
  }
  __syncthreads();
  for (int i = t; i < NGRAPH * 3; i += 256)
    if (ls[i] != 0.f) atomicAdd(&gsum[i], ls[i]);
  for (int i = t; i < NGRAPH; i += 256)
    if (lc[i] != 0.f) atomicAdd(&gcnt[i], lc[i]);
}

// 1 block, 64 threads: per-graph mean + 2-layer MLP
__global__ __launch_bounds__(64) void k_mlp(const float* __restrict__ gsum,
                                            const float* __restrict__ gcnt,
                                            const float* __restrict__ Wr1,
                                            const float* __restrict__ br1,
                                            const float* __restrict__ Wr2,
                                            const float* __restrict__ br2,
                                            float* __restrict__ out) {
  int t = threadIdx.x;
  if (t >= NGRAPH) return;
  float cnt = fmaxf(gcnt[t], 1.f);
  float g0 = gsum[t * 3 + 0] / cnt;
  float g1 = gsum[t * 3 + 1] / cnt;
  float g2 = gsum[t * 3 + 2] / cnt;
  float o0 = br2[0], o1 = br2[1], o2 = br2[2];
  for (int j = 0; j < 64; ++j) {
    float hj = g0 * Wr1[j] + g1 * Wr1[64 + j] + g2 * Wr1[128 + j] + br1[j];
    hj = fmaxf(hj, 0.f);
    o0 = fmaf(hj, Wr2[j * 3 + 0], o0);
    o1 = fmaf(hj, Wr2[j * 3 + 1], o1);
    o2 = fmaf(hj, Wr2[j * 3 + 2], o2);
  }
  out[t * 3 + 0] = o0;
  out[t * 3 + 1] = o1;
  out[t * 3 + 2] = o2;
}

// ---------------------------------------------------------------------------
extern "C" void kernel_launch(void* const* d_in, const int* in_sizes, int n_in,
                              void* d_out, int out_size, void* d_ws, size_t ws_size,
                              hipStream_t stream) {
  const float* x    = (const float*)d_in[0];
  const int*   ei   = (const int*)d_in[1];
  const int*   batch= (const int*)d_in[2];
  const float* W1l  = (const float*)d_in[3];
  const float* W1r  = (const float*)d_in[4];
  const float* att1 = (const float*)d_in[5];
  const float* b1   = (const float*)d_in[6];
  const float* W2l  = (const float*)d_in[7];
  const float* W2r  = (const float*)d_in[8];
  const float* att2 = (const float*)d_in[9];
  const float* b2   = (const float*)d_in[10];
  const float* Wr1  = (const float*)d_in[11];
  const float* br1  = (const float*)d_in[12];
  const float* Wr2  = (const float*)d_in[13];
  const float* br2  = (const float*)d_in[14];
  float* out = (float*)d_out;

  const int N  = in_sizes[0] / 128;
  const int E  = in_sizes[1] / 2;
  const int Et = E + N;

  char* p = (char*)d_ws;
  auto alloc = [&](size_t bytes) -> char* {
    char* r = p;
    p += (bytes + 255) & ~(size_t)255;
    return r;
  };
  float*    xl1    = (float*)alloc((size_t)N * 128 * 4);
  float*    xr1    = (float*)alloc((size_t)N * 128 * 4);
  int*      row_ptr= (int*)alloc((size_t)(N + 1) * 4);
  int*      csr_src= (int*)alloc((size_t)Et * 4);
  // zero-init group (one memset): deg | cursor | gsum | gcnt
  char*     z0     = p;
  int*      deg    = (int*)alloc((size_t)N * 4);
  int*      cursor = (int*)alloc((size_t)N * 4);
  float*    gsum   = (float*)alloc(NGRAPH * 3 * 4);
  float*    gcnt   = (float*)alloc(NGRAPH * 4);
  size_t    zbytes = (size_t)(p - z0);
  float*    xl2    = (float*)alloc((size_t)N * 4 * 4);
  float*    xr2    = (float*)alloc((size_t)N * 4 * 4);

  hipMemsetAsync(z0, 0, zbytes, stream);
  hipLaunchKernelGGL(k_deg, dim3((Et + 255) / 256), dim3(256), 0, stream, ei, E, Et, deg);
  hipLaunchKernelGGL(k_scan, dim3(1), dim3(1024), 0, stream, deg, row_ptr, N);
  hipLaunchKernelGGL(k_fill, dim3((Et + 255) / 256), dim3(256), 0, stream,
                     ei, E, Et, row_ptr, cursor, csr_src);
  hipLaunchKernelGGL(k_gemm128, dim3((N + 127) / 128, 2), dim3(256), 0, stream,
                     x, W1l, W1r, xl1, xr1, N);
  int waves1 = (N + 1) / 2;
  hipLaunchKernelGGL(k_fused1, dim3((waves1 * 64 + 255) / 256), dim3(256), 0, stream,
                     xl1, xr1, row_ptr, csr_src, att1, b1, W2l, W2r, xl2, xr2, N);
  hipLaunchKernelGGL(k_fused2, dim3((N * 16 + 255) / 256), dim3(256), 0, stream,
                     xl2, xr2, row_ptr, csr_src, att2, b2, batch, gsum, gcnt, N);
  hipLaunchKernelGGL(k_mlp, dim3(1), dim3(64), 0, stream,
                     gsum, gcnt, Wr1, br1, Wr2, br2, out);
}

// Round 7
// 337.303 us; speedup vs baseline: 3.3456x; 1.0159x over previous
//
#include <hip/hip_runtime.h>

// ---------------------------------------------------------------------------
// GATv2 (2 layers) + mean-pool + MLP for MI355X. fp32 throughout.
// N=50000 nodes, E=800000 edges (+N self loops), IN=128, HID=64, HEADS=2,
// OUT=3, 64 graphs. Output: [64,3] float32.
// R1: k_agg2 pool atomic storm fixed (LDS pre-reduction). 1128 -> 803 us.
// R2: CSR + per-node online softmax; edge phases fused.   803 -> 515 us.
// R3: fused1 2-edge ILP + reg src cache + W2-proj fused.   515 -> 394 us.
// R4: fused1 2 nodes/wave + 4-edge ILP + batched softmax.  394 -> 368 us.
// R5: gemm 128x128 reg-blocked (LDS 72KB->16KB).            368 -> 343 us.
// R6: fused1 logit reduce -> DPP row_ror on VALU pipe (was 16 ds-shfl/iter),
//     exps -> exp2 domain (att pre-scaled by log2e; saves mul per exp).
//     gemm: 64x128 tile 4x8 micro (1564 blocks, 6.1/CU; 2-way banks only).
// ---------------------------------------------------------------------------

#define NGRAPH 64
#define LOG2E 1.4426950408889634f

__device__ __forceinline__ void edge_sd(const int* __restrict__ ei, int E, int e,
                                        int& s, int& d) {
  if (e < E) { s = ei[e]; d = ei[E + e]; }
  else       { s = e - E; d = s; }
}

// v_mov_dpp row_ror:k (16-lane rows). Valid reduce permutation for
// commutative ops; leaves every lane of the row with the full result.
#define DPP_ROR(C, x) \
  __int_as_float(__builtin_amdgcn_update_dpp(0, __float_as_int(x), (0x120 | C), 0xF, 0xF, false))

__device__ __forceinline__ float rowsum16(float v) {
  v += DPP_ROR(8, v);
  v += DPP_ROR(4, v);
  v += DPP_ROR(2, v);
  v += DPP_ROR(1, v);
  return v;
}

// ---------------------------------------------------------------------------
__global__ void k_deg(const int* __restrict__ ei, int E, int Et, int* __restrict__ deg) {
  int e = blockIdx.x * blockDim.x + threadIdx.x;
  if (e >= Et) return;
  int s, d; edge_sd(ei, E, e, s, d);
  atomicAdd(&deg[d], 1);
}

// single block, 1024 threads: exclusive scan of deg -> row_ptr[0..n]
__global__ __launch_bounds__(1024) void k_scan(const int* __restrict__ deg,
                                               int* __restrict__ row_ptr, int n) {
  __shared__ int sdata[1024];
  int t = threadIdx.x;
  const int chunk = 52;
  int base = t * chunk;
  int end = min(base + chunk, n);
  int sum = 0;
  if (base + chunk <= n) {
#pragma unroll
    for (int i = 0; i < 13; ++i) {
      int4 d = *(const int4*)&deg[base + i * 4];
      sum += d.x + d.y + d.z + d.w;
    }
  } else {
    for (int i = base; i < end; ++i) sum += deg[i];
  }
  sdata[t] = sum;
  __syncthreads();
  for (int off = 1; off < 1024; off <<= 1) {
    int v = (t >= off) ? sdata[t - off] : 0;
    __syncthreads();
    sdata[t] += v;
    __syncthreads();
  }
  int run = sdata[t] - sum;  // exclusive prefix of this chunk
  if (base + chunk <= n) {
#pragma unroll
    for (int i = 0; i < 13; ++i) {
      int4 d = *(const int4*)&deg[base + i * 4];
      int4 r;
      r.x = run;       r.y = run + d.x;
      r.z = r.y + d.y; r.w = r.z + d.z;
      *(int4*)&row_ptr[base + i * 4] = r;
      run = r.w + d.w;
    }
  } else {
    for (int i = base; i < end; ++i) { row_ptr[i] = run; run += deg[i]; }
  }
  if (t == 1023) row_ptr[n] = sdata[1023];
}

__global__ void k_fill(const int* __restrict__ ei, int E, int Et,
                       const int* __restrict__ row_ptr, int* __restrict__ cursor,
                       int* __restrict__ csr_src) {
  int e = blockIdx.x * blockDim.x + threadIdx.x;
  if (e >= Et) return;
  int s, d; edge_sd(ei, E, e, s, d);
  int pos = atomicAdd(&cursor[d], 1);
  csr_src[row_ptr[d] + pos] = s;
}

// ---------------------------------------------------------------------------
// R6: out[n,128] = x[n,128] @ W[128,128], blockIdx.y selects Wl/Wr.
// 64x128 block tile, BK=16, 256 threads, 4x8 micro-tile (cols split
// {tx*4, 64+tx*4} -> only 2-way LDS bank aliasing, which is free).
__global__ __launch_bounds__(256) void k_gemm128(const float* __restrict__ x,
                                                 const float* __restrict__ Wl,
                                                 const float* __restrict__ Wr,
                                                 float* __restrict__ outl,
                                                 float* __restrict__ outr, int n) {
  __shared__ __align__(16) float xs[16][68];   // x tile transposed: [k][row]
  __shared__ __align__(16) float ws[16][132];  // W tile: [k][col]
  const float* W = blockIdx.y ? Wr : Wl;
  float* out = blockIdx.y ? outr : outl;
  int t = threadIdx.x;
  int tx = t & 15, ty = t >> 4;     // tx: col group 0..15, ty: row group 0..15
  int r0 = blockIdx.x * 64;
  float acc[4][8] = {};

  int sr = t >> 2;           // x staging: row 0..63
  int sk = (t & 3) * 4;      // k-quad
  int wk = t >> 5;           // W staging: k row 0..7
  int wc = (t & 31) * 4;     // col quad

  for (int k0 = 0; k0 < 128; k0 += 16) {
    // issue global loads before the barrier so they fly through the drain
    int gr = r0 + sr;
    float4 xv = make_float4(0.f, 0.f, 0.f, 0.f);
    if (gr < n) xv = *(const float4*)&x[(size_t)gr * 128 + k0 + sk];
    float4 wv0 = *(const float4*)&W[(size_t)(k0 + wk) * 128 + wc];
    float4 wv1 = *(const float4*)&W[(size_t)(k0 + wk + 8) * 128 + wc];
    __syncthreads();
    xs[sk + 0][sr] = xv.x;
    xs[sk + 1][sr] = xv.y;
    xs[sk + 2][sr] = xv.z;
    xs[sk + 3][sr] = xv.w;
    *(float4*)&ws[wk][wc] = wv0;
    *(float4*)&ws[wk + 8][wc] = wv1;
    __syncthreads();
#pragma unroll
    for (int k = 0; k < 16; ++k) {
      float4 av = *(const float4*)&xs[k][ty * 4];
      float4 b0 = *(const float4*)&ws[k][tx * 4];
      float4 b1 = *(const float4*)&ws[k][64 + tx * 4];
      float a[4] = {av.x, av.y, av.z, av.w};
      float b[8] = {b0.x, b0.y, b0.z, b0.w, b1.x, b1.y, b1.z, b1.w};
#pragma unroll
      for (int i = 0; i < 4; ++i)
#pragma unroll
        for (int j = 0; j < 8; ++j)
          acc[i][j] = fmaf(a[i], b[j], acc[i][j]);
    }
  }
#pragma unroll
  for (int i = 0; i < 4; ++i) {
    int gr = r0 + ty * 4 + i;
    if (gr < n) {
      *(float4*)&out[(size_t)gr * 128 + tx * 4] =
          make_float4(acc[i][0], acc[i][1], acc[i][2], acc[i][3]);
      *(float4*)&out[(size_t)gr * 128 + 64 + tx * 4] =
          make_float4(acc[i][4], acc[i][5], acc[i][6], acc[i][7]);
    }
  }
}

// ---------------------------------------------------------------------------
// fused layer-1 edge phase + layer-2 input projection.
// TWO nodes per wave: lanes 0-31 = node A, 32-63 = node B; lane holds 4
// channels; 16-lane head groups = DPP rows. 4 edges/iter, DPP rotate-reduce
// for logits, batched online softmax in exp2 domain (att pre-scaled log2e).
// Out-of-range edges: index clamped (L1-hot), logit -1e30 -> weight 0.
__global__ __launch_bounds__(256) void k_fused1(const float* __restrict__ xl,
                                                const float* __restrict__ xr,
                                                const int* __restrict__ row_ptr,
                                                const int* __restrict__ csr_src,
                                                const float* __restrict__ att1,
                                                const float* __restrict__ b1,
                                                const float* __restrict__ W2l,
                                                const float* __restrict__ W2r,
                                                float* __restrict__ xl2,
                                                float* __restrict__ xr2, int n) {
  int wid  = (blockIdx.x * 256 + threadIdx.x) >> 6;
  int lane = threadIdx.x & 63;
  int sub  = lane & 31;
  int node = wid * 2 + (lane >> 5);
  bool valid = node < n;
  int nc = valid ? node : 0;
  int ch = sub * 4;
  float4 xrv = *(const float4*)&xr[(size_t)nc * 128 + ch];
  float4 atv = *(const float4*)&att1[ch];
  atv.x *= LOG2E; atv.y *= LOG2E; atv.z *= LOG2E; atv.w *= LOG2E;
  int s0 = row_ptr[nc];
  int deg = valid ? (row_ptr[nc + 1] - s0) : 1;  // every node has self-loop
  int dm1 = deg - 1;
  int maxdeg = max(deg, __shfl_xor(deg, 32));  // wave-uniform loop bound

  float m = -1e30f, l = 0.f;
  float4 acc = make_float4(0.f, 0.f, 0.f, 0.f);

  int sA = csr_src[s0 + min(0, dm1)];
  int sB = csr_src[s0 + min(1, dm1)];
  int sC = csr_src[s0 + min(2, dm1)];
  int sD = csr_src[s0 + min(3, dm1)];

  for (int e = 0; e < maxdeg; e += 4) {
    float4 xa = *(const float4*)&xl[(size_t)sA * 128 + ch];
    float4 xb = *(const float4*)&xl[(size_t)sB * 128 + ch];
    float4 xc = *(const float4*)&xl[(size_t)sC * 128 + ch];
    float4 xd = *(const float4*)&xl[(size_t)sD * 128 + ch];
    int e4 = e + 4;
    sA = csr_src[s0 + min(e4 + 0, dm1)];
    sB = csr_src[s0 + min(e4 + 1, dm1)];
    sC = csr_src[s0 + min(e4 + 2, dm1)];
    sD = csr_src[s0 + min(e4 + 3, dm1)];

    float t0, t1, t2, t3;
#define LOGIT(p, v)                                                     \
    t0 = v.x + xrv.x; t0 = fmaxf(t0, 0.2f * t0);                        \
    t1 = v.y + xrv.y; t1 = fmaxf(t1, 0.2f * t1);                        \
    t2 = v.z + xrv.z; t2 = fmaxf(t2, 0.2f * t2);                        \
    t3 = v.w + xrv.w; t3 = fmaxf(t3, 0.2f * t3);                        \
    p = fmaf(t3, atv.w, fmaf(t2, atv.z, fmaf(t1, atv.y, t0 * atv.x)));
    float pa, pb, pc, pd;
    LOGIT(pa, xa) LOGIT(pb, xb) LOGIT(pc, xc) LOGIT(pd, xd)
#undef LOGIT
    pa = rowsum16(pa);
    pb = rowsum16(pb);
    pc = rowsum16(pc);
    pd = rowsum16(pd);
    pa = (e + 0 < deg) ? pa : -1e30f;
    pb = (e + 1 < deg) ? pb : -1e30f;
    pc = (e + 2 < deg) ? pc : -1e30f;
    pd = (e + 3 < deg) ? pd : -1e30f;
    float mn = fmaxf(m, fmaxf(fmaxf(pa, pb), fmaxf(pc, pd)));
    float sc = exp2f(m - mn);
    float wa = exp2f(pa - mn);
    float wb = exp2f(pb - mn);
    float wc = exp2f(pc - mn);
    float wd = exp2f(pd - mn);
    acc.x = fmaf(wd, xd.x, fmaf(wc, xc.x, fmaf(wb, xb.x, fmaf(wa, xa.x, acc.x * sc))));
    acc.y = fmaf(wd, xd.y, fmaf(wc, xc.y, fmaf(wb, xb.y, fmaf(wa, xa.y, acc.y * sc))));
    acc.z = fmaf(wd, xd.z, fmaf(wc, xc.z, fmaf(wb, xb.z, fmaf(wa, xa.z, acc.z * sc))));
    acc.w = fmaf(wd, xd.w, fmaf(wc, xc.w, fmaf(wb, xb.w, fmaf(wa, xa.w, acc.w * sc))));
    l = fmaf(l, sc, wa + wb + wc + wd);
    m = mn;
  }

  float inv = 1.f / (l + 1e-16f);
  float4 b1v = *(const float4*)&b1[ch];
  float4 h;
  h.x = acc.x * inv + b1v.x; h.x = h.x > 0.f ? h.x : expm1f(h.x);
  h.y = acc.y * inv + b1v.y; h.y = h.y > 0.f ? h.y : expm1f(h.y);
  h.z = acc.z * inv + b1v.z; h.z = h.z > 0.f ? h.z : expm1f(h.z);
  h.w = acc.w * inv + b1v.w; h.w = h.w > 0.f ? h.w : expm1f(h.w);

  float4 u0 = *(const float4*)&W2l[ch * 3 + 0];
  float4 u1 = *(const float4*)&W2l[ch * 3 + 4];
  float4 u2 = *(const float4*)&W2l[ch * 3 + 8];
  float al0 = fmaf(h.w, u2.y, fmaf(h.z, u1.z, fmaf(h.y, u0.w, h.x * u0.x)));
  float al1 = fmaf(h.w, u2.z, fmaf(h.z, u1.w, fmaf(h.y, u1.x, h.x * u0.y)));
  float al2 = fmaf(h.w, u2.w, fmaf(h.z, u2.x, fmaf(h.y, u1.y, h.x * u0.z)));
  float4 v0 = *(const float4*)&W2r[ch * 3 + 0];
  float4 v1 = *(const float4*)&W2r[ch * 3 + 4];
  float4 v2 = *(const float4*)&W2r[ch * 3 + 8];
  float ar0 = fmaf(h.w, v2.y, fmaf(h.z, v1.z, fmaf(h.y, v0.w, h.x * v0.x)));
  float ar1 = fmaf(h.w, v2.z, fmaf(h.z, v1.w, fmaf(h.y, v1.x, h.x * v0.y)));
  float ar2 = fmaf(h.w, v2.w, fmaf(h.z, v2.x, fmaf(h.y, v1.y, h.x * v0.z)));
#pragma unroll
  for (int off = 1; off < 32; off <<= 1) {
    al0 += __shfl_xor(al0, off); al1 += __shfl_xor(al1, off);
    al2 += __shfl_xor(al2, off); ar0 += __shfl_xor(ar0, off);
    ar1 += __shfl_xor(ar1, off); ar2 += __shfl_xor(ar2, off);
  }
  if (valid && sub == 0) {
    *(float4*)&xl2[node * 4] = make_float4(al0, al1, al2, 0.f);
    *(float4*)&xr2[node * 4] = make_float4(ar0, ar1, ar2, 0.f);
  }
}

// ---------------------------------------------------------------------------
// fused layer-2 edge phase + mean-pool. 16 lanes per node (= one DPP row);
// per-lane online softmax (exp2 domain) over a 16-stride slice, DPP rotate
// merge of (m,l,acc3) states. Pool pre-reduced in LDS.
__global__ __launch_bounds__(256) void k_fused2(const float* __restrict__ xl2,
                                                const float* __restrict__ xr2,
                                                const int* __restrict__ row_ptr,
                                                const int* __restrict__ csr_src,
                                                const float* __restrict__ att2,
                                                const float* __restrict__ b2,
                                                const int* __restrict__ batch,
                                                float* __restrict__ gsum,
                                                float* __restrict__ gcnt, int n) {
  __shared__ float ls[NGRAPH * 3];
  __shared__ float lc[NGRAPH];
  int t = threadIdx.x;
  for (int i = t; i < NGRAPH * 3; i += 256) ls[i] = 0.f;
  for (int i = t; i < NGRAPH; i += 256) lc[i] = 0.f;
  __syncthreads();

  int node = (blockIdx.x * 256 + t) >> 4;  // 16 nodes per block
  int lane = t & 15;
  if (node < n) {
    float4 xrv = *(const float4*)&xr2[node * 4];
    float c0 = att2[0] * LOG2E, c1 = att2[1] * LOG2E, c2 = att2[2] * LOG2E;
    int s0 = row_ptr[node], s1 = row_ptr[node + 1];
    float m = -1e30f, l = 0.f, a0 = 0.f, a1 = 0.f, a2 = 0.f;
    for (int slot = s0 + lane; slot < s1; slot += 16) {
      int s = csr_src[slot];
      float4 xlv = *(const float4*)&xl2[s * 4];
      float t0 = xlv.x + xrv.x; t0 = fmaxf(t0, 0.2f * t0);
      float t1 = xlv.y + xrv.y; t1 = fmaxf(t1, 0.2f * t1);
      float t2 = xlv.z + xrv.z; t2 = fmaxf(t2, 0.2f * t2);
      float p = fmaf(t2, c2, fmaf(t1, c1, t0 * c0));
      float mn = fmaxf(m, p);
      float sc = exp2f(m - mn);
      float w  = exp2f(p - mn);
      a0 = a0 * sc + w * xlv.x;
      a1 = a1 * sc + w * xlv.y;
      a2 = a2 * sc + w * xlv.z;
      l = l * sc + w;
      m = mn;
    }
#define MERGE(C)                                                        \
    {                                                                   \
      float m2 = DPP_ROR(C, m);                                         \
      float l2 = DPP_ROR(C, l);                                         \
      float b0 = DPP_ROR(C, a0);                                        \
      float b1v = DPP_ROR(C, a1);                                       \
      float b2v = DPP_ROR(C, a2);                                       \
      float mn = fmaxf(m, m2);                                          \
      float sA = exp2f(m - mn);                                         \
      float sB = exp2f(m2 - mn);                                        \
      a0 = a0 * sA + b0 * sB;                                           \
      a1 = a1 * sA + b1v * sB;                                          \
      a2 = a2 * sA + b2v * sB;                                          \
      l = l * sA + l2 * sB;                                             \
      m = mn;                                                           \
    }
    MERGE(8) MERGE(4) MERGE(2) MERGE(1)
#undef MERGE
    if (lane == 0) {
      float inv = 1.f / (l + 1e-16f);
      float o0 = a0 * inv + b2[0];
      float o1 = a1 * inv + b2[1];
      float o2 = a2 * inv + b2[2];
      int b = batch[node];
      atomicAdd(&ls[b * 3 + 0], o0);
      atomicAdd(&ls[b * 3 + 1], o1);
      atomicAdd(&ls[b * 3 + 2], o2);
      atomicAdd(&lc[b], 1.f);
    }
  }
  __syncthreads();
  for (int i = t; i < NGRAPH * 3; i += 256)
    if (ls[i] != 0.f) atomicAdd(&gsum[i], ls[i]);
  for (int i = t; i < NGRAPH; i += 256)
    if (lc[i] != 0.f) atomicAdd(&gcnt[i], lc[i]);
}

// 1 block, 64 threads: per-graph mean + 2-layer MLP
__global__ __launch_bounds__(64) void k_mlp(const float* __restrict__ gsum,
                                            const float* __restrict__ gcnt,
                                            const float* __restrict__ Wr1,
                                            const float* __restrict__ br1,
                                            const float* __restrict__ Wr2,
                                            const float* __restrict__ br2,
                                            float* __restrict__ out) {
  int t = threadIdx.x;
  if (t >= NGRAPH) return;
  float cnt = fmaxf(gcnt[t], 1.f);
  float g0 = gsum[t * 3 + 0] / cnt;
  float g1 = gsum[t * 3 + 1] / cnt;
  float g2 = gsum[t * 3 + 2] / cnt;
  float o0 = br2[0], o1 = br2[1], o2 = br2[2];
  for (int j = 0; j < 64; ++j) {
    float hj = g0 * Wr1[j] + g1 * Wr1[64 + j] + g2 * Wr1[128 + j] + br1[j];
    hj = fmaxf(hj, 0.f);
    o0 = fmaf(hj, Wr2[j * 3 + 0], o0);
    o1 = fmaf(hj, Wr2[j * 3 + 1], o1);
    o2 = fmaf(hj, Wr2[j * 3 + 2], o2);
  }
  out[t * 3 + 0] = o0;
  out[t * 3 + 1] = o1;
  out[t * 3 + 2] = o2;
}

// ---------------------------------------------------------------------------
extern "C" void kernel_launch(void* const* d_in, const int* in_sizes, int n_in,
                              void* d_out, int out_size, void* d_ws, size_t ws_size,
                              hipStream_t stream) {
  const float* x    = (const float*)d_in[0];
  const int*   ei   = (const int*)d_in[1];
  const int*   batch= (const int*)d_in[2];
  const float* W1l  = (const float*)d_in[3];
  const float* W1r  = (const float*)d_in[4];
  const float* att1 = (const float*)d_in[5];
  const float* b1   = (const float*)d_in[6];
  const float* W2l  = (const float*)d_in[7];
  const float* W2r  = (const float*)d_in[8];
  const float* att2 = (const float*)d_in[9];
  const float* b2   = (const float*)d_in[10];
  const float* Wr1  = (const float*)d_in[11];
  const float* br1  = (const float*)d_in[12];
  const float* Wr2  = (const float*)d_in[13];
  const float* br2  = (const float*)d_in[14];
  float* out = (float*)d_out;

  const int N  = in_sizes[0] / 128;
  const int E  = in_sizes[1] / 2;
  const int Et = E + N;

  char* p = (char*)d_ws;
  auto alloc = [&](size_t bytes) -> char* {
    char* r = p;
    p += (bytes + 255) & ~(size_t)255;
    return r;
  };
  float*    xl1    = (float*)alloc((size_t)N * 128 * 4);
  float*    xr1    = (float*)alloc((size_t)N * 128 * 4);
  int*      row_ptr= (int*)alloc((size_t)(N + 1) * 4);
  int*      csr_src= (int*)alloc((size_t)Et * 4);
  // zero-init group (one memset): deg | cursor | gsum | gcnt
  char*     z0     = p;
  int*      deg    = (int*)alloc((size_t)N * 4);
  int*      cursor = (int*)alloc((size_t)N * 4);
  float*    gsum   = (float*)alloc(NGRAPH * 3 * 4);
  float*    gcnt   = (float*)alloc(NGRAPH * 4);
  size_t    zbytes = (size_t)(p - z0);
  float*    xl2    = (float*)alloc((size_t)N * 4 * 4);
  float*    xr2    = (float*)alloc((size_t)N * 4 * 4);

  hipMemsetAsync(z0, 0, zbytes, stream);
  hipLaunchKernelGGL(k_deg, dim3((Et + 255) / 256), dim3(256), 0, stream, ei, E, Et, deg);
  hipLaunchKernelGGL(k_scan, dim3(1), dim3(1024), 0, stream, deg, row_ptr, N);
  hipLaunchKernelGGL(k_fill, dim3((Et + 255) / 256), dim3(256), 0, stream,
                     ei, E, Et, row_ptr, cursor, csr_src);
  hipLaunchKernelGGL(k_gemm128, dim3((N + 63) / 64, 2), dim3(256), 0, stream,
                     x, W1l, W1r, xl1, xr1, N);
  int waves1 = (N + 1) / 2;
  hipLaunchKernelGGL(k_fused1, dim3((waves1 * 64 + 255) / 256), dim3(256), 0, stream,
                     xl1, xr1, row_ptr, csr_src, att1, b1, W2l, W2r, xl2, xr2, N);
  hipLaunchKernelGGL(k_fused2, dim3((N * 16 + 255) / 256), dim3(256), 0, stream,
                     xl2, xr2, row_ptr, csr_src, att2, b2, batch, gsum, gcnt, N);
  hipLaunchKernelGGL(k_mlp, dim3(1), dim3(64), 0, stream,
                     gsum, gcnt, Wr1, br1, Wr2, br2, out);
}

// Round 8
// 335.467 us; speedup vs baseline: 3.3640x; 1.0055x over previous
//
#include <hip/hip_runtime.h>

// ---------------------------------------------------------------------------
// GATv2 (2 layers) + mean-pool + MLP for MI355X. fp32 throughout.
// N=50000 nodes, E=800000 edges (+N self loops), IN=128, HID=64, HEADS=2,
// OUT=3, 64 graphs. Output: [64,3] float32.
// R1: k_agg2 pool atomic storm fixed (LDS pre-reduction). 1128 -> 803 us.
// R2: CSR + per-node online softmax; edge phases fused.   803 -> 515 us.
// R3: fused1 2-edge ILP + reg src cache + W2-proj fused.   515 -> 394 us.
// R4: fused1 2 nodes/wave + 4-edge ILP + batched softmax.  394 -> 368 us.
// R5: gemm 128x128 reg-blocked (LDS 72KB->16KB).            368 -> 343 us.
// R6: DPP rotate-reduce + exp2 domain; gemm 64x128/4x8.     343 -> 337 us.
// R7: fused1 VALU-saturated (73% busy) + latency stalls -> clamp-free 8-edge
//     pipelined main loop (8 gathers in flight, 1 softmax batch/8 edges,
//     uint32 SADDR gather addressing), 4-edge clamped tail. k_deg dst-only.
// ---------------------------------------------------------------------------

#define NGRAPH 64
#define LOG2E 1.4426950408889634f

// v_mov_dpp row_ror:k (16-lane rows). Valid reduce permutation for
// commutative ops; leaves every lane of the row with the full result.
#define DPP_ROR(C, x) \
  __int_as_float(__builtin_amdgcn_update_dpp(0, __float_as_int(x), (0x120 | C), 0xF, 0xF, false))

__device__ __forceinline__ float rowsum16(float v) {
  v += DPP_ROR(8, v);
  v += DPP_ROR(4, v);
  v += DPP_ROR(2, v);
  v += DPP_ROR(1, v);
  return v;
}

// ---------------------------------------------------------------------------
__global__ void k_deg(const int* __restrict__ ei, int E, int Et, int* __restrict__ deg) {
  int e = blockIdx.x * blockDim.x + threadIdx.x;
  if (e >= Et) return;
  int d = (e < E) ? ei[E + e] : (e - E);  // dst only
  atomicAdd(&deg[d], 1);
}

// single block, 1024 threads: exclusive scan of deg -> row_ptr[0..n]
__global__ __launch_bounds__(1024) void k_scan(const int* __restrict__ deg,
                                               int* __restrict__ row_ptr, int n) {
  __shared__ int sdata[1024];
  int t = threadIdx.x;
  const int chunk = 52;
  int base = t * chunk;
  int end = min(base + chunk, n);
  int sum = 0;
  if (base + chunk <= n) {
#pragma unroll
    for (int i = 0; i < 13; ++i) {
      int4 d = *(const int4*)&deg[base + i * 4];
      sum += d.x + d.y + d.z + d.w;
    }
  } else {
    for (int i = base; i < end; ++i) sum += deg[i];
  }
  sdata[t] = sum;
  __syncthreads();
  for (int off = 1; off < 1024; off <<= 1) {
    int v = (t >= off) ? sdata[t - off] : 0;
    __syncthreads();
    sdata[t] += v;
    __syncthreads();
  }
  int run = sdata[t] - sum;  // exclusive prefix of this chunk
  if (base + chunk <= n) {
#pragma unroll
    for (int i = 0; i < 13; ++i) {
      int4 d = *(const int4*)&deg[base + i * 4];
      int4 r;
      r.x = run;       r.y = run + d.x;
      r.z = r.y + d.y; r.w = r.z + d.z;
      *(int4*)&row_ptr[base + i * 4] = r;
      run = r.w + d.w;
    }
  } else {
    for (int i = base; i < end; ++i) { row_ptr[i] = run; run += deg[i]; }
  }
  if (t == 1023) row_ptr[n] = sdata[1023];
}

__global__ void k_fill(const int* __restrict__ ei, int E, int Et,
                       const int* __restrict__ row_ptr, int* __restrict__ cursor,
                       int* __restrict__ csr_src) {
  int e = blockIdx.x * blockDim.x + threadIdx.x;
  if (e >= Et) return;
  int s, d;
  if (e < E) { s = ei[e]; d = ei[E + e]; }
  else       { s = e - E; d = s; }
  int pos = atomicAdd(&cursor[d], 1);
  csr_src[row_ptr[d] + pos] = s;
}

// ---------------------------------------------------------------------------
// out[n,128] = x[n,128] @ W[128,128], blockIdx.y selects Wl/Wr.
// 64x128 block tile, BK=16, 256 threads, 4x8 micro-tile.
__global__ __launch_bounds__(256) void k_gemm128(const float* __restrict__ x,
                                                 const float* __restrict__ Wl,
                                                 const float* __restrict__ Wr,
                                                 float* __restrict__ outl,
                                                 float* __restrict__ outr, int n) {
  __shared__ __align__(16) float xs[16][68];   // x tile transposed: [k][row]
  __shared__ __align__(16) float ws[16][132];  // W tile: [k][col]
  const float* W = blockIdx.y ? Wr : Wl;
  float* out = blockIdx.y ? outr : outl;
  int t = threadIdx.x;
  int tx = t & 15, ty = t >> 4;
  int r0 = blockIdx.x * 64;
  float acc[4][8] = {};

  int sr = t >> 2;           // x staging: row 0..63
  int sk = (t & 3) * 4;      // k-quad
  int wk = t >> 5;           // W staging: k row 0..7
  int wc = (t & 31) * 4;     // col quad

  for (int k0 = 0; k0 < 128; k0 += 16) {
    int gr = r0 + sr;
    float4 xv = make_float4(0.f, 0.f, 0.f, 0.f);
    if (gr < n) xv = *(const float4*)&x[(size_t)gr * 128 + k0 + sk];
    float4 wv0 = *(const float4*)&W[(size_t)(k0 + wk) * 128 + wc];
    float4 wv1 = *(const float4*)&W[(size_t)(k0 + wk + 8) * 128 + wc];
    __syncthreads();
    xs[sk + 0][sr] = xv.x;
    xs[sk + 1][sr] = xv.y;
    xs[sk + 2][sr] = xv.z;
    xs[sk + 3][sr] = xv.w;
    *(float4*)&ws[wk][wc] = wv0;
    *(float4*)&ws[wk + 8][wc] = wv1;
    __syncthreads();
#pragma unroll
    for (int k = 0; k < 16; ++k) {
      float4 av = *(const float4*)&xs[k][ty * 4];
      float4 b0 = *(const float4*)&ws[k][tx * 4];
      float4 b1 = *(const float4*)&ws[k][64 + tx * 4];
      float a[4] = {av.x, av.y, av.z, av.w};
      float b[8] = {b0.x, b0.y, b0.z, b0.w, b1.x, b1.y, b1.z, b1.w};
#pragma unroll
      for (int i = 0; i < 4; ++i)
#pragma unroll
        for (int j = 0; j < 8; ++j)
          acc[i][j] = fmaf(a[i], b[j], acc[i][j]);
    }
  }
#pragma unroll
  for (int i = 0; i < 4; ++i) {
    int gr = r0 + ty * 4 + i;
    if (gr < n) {
      *(float4*)&out[(size_t)gr * 128 + tx * 4] =
          make_float4(acc[i][0], acc[i][1], acc[i][2], acc[i][3]);
      *(float4*)&out[(size_t)gr * 128 + 64 + tx * 4] =
          make_float4(acc[i][4], acc[i][5], acc[i][6], acc[i][7]);
    }
  }
}

// ---------------------------------------------------------------------------
// fused layer-1 edge phase + layer-2 input projection.
// TWO nodes per wave: lanes 0-31 = node A, 32-63 = node B; lane holds 4
// channels; 16-lane head groups = DPP rows. Main loop: 8 edges/iter with NO
// clamping (e+8 <= min(degA,degB)), 8 gathers in flight, one batched online
// softmax (exp2 domain) per 8 edges. Tail: 4-edge clamped+masked iterations.
__global__ __launch_bounds__(256) void k_fused1(const float* __restrict__ xl,
                                                const float* __restrict__ xr,
                                                const int* __restrict__ row_ptr,
                                                const int* __restrict__ csr_src,
                                                const float* __restrict__ att1,
                                                const float* __restrict__ b1,
                                                const float* __restrict__ W2l,
                                                const float* __restrict__ W2r,
                                                float* __restrict__ xl2,
                                                float* __restrict__ xr2, int n) {
  int wid  = (blockIdx.x * 256 + threadIdx.x) >> 6;
  int lane = threadIdx.x & 63;
  int sub  = lane & 31;
  int node = wid * 2 + (lane >> 5);
  bool valid = node < n;
  int nc = valid ? node : 0;
  int ch = sub * 4;
  const char* xlb = (const char*)xl;
  unsigned chb = (unsigned)ch * 4u;
  float4 xrv = *(const float4*)&xr[(size_t)nc * 128 + ch];
  float4 atv = *(const float4*)&att1[ch];
  atv.x *= LOG2E; atv.y *= LOG2E; atv.z *= LOG2E; atv.w *= LOG2E;
  int s0 = row_ptr[nc];
  int deg = valid ? (row_ptr[nc + 1] - s0) : 1;  // every node has self-loop
  int odeg = __shfl_xor(deg, 32);
  int mindeg = min(deg, odeg);  // wave-uniform
  int maxdeg = max(deg, odeg);  // wave-uniform
  const int* sp = csr_src + s0;

  float m = -1e30f, l = 0.f;
  float4 acc = make_float4(0.f, 0.f, 0.f, 0.f);

  float t0, t1, t2, t3;
#define LOGIT(p, v)                                                     \
    t0 = v.x + xrv.x; t0 = fmaxf(t0, 0.2f * t0);                        \
    t1 = v.y + xrv.y; t1 = fmaxf(t1, 0.2f * t1);                        \
    t2 = v.z + xrv.z; t2 = fmaxf(t2, 0.2f * t2);                        \
    t3 = v.w + xrv.w; t3 = fmaxf(t3, 0.2f * t3);                        \
    p = fmaf(t3, atv.w, fmaf(t2, atv.z, fmaf(t1, atv.y, t0 * atv.x)));

  int e = 0;
  // ---- main loop: 8 edges, clamp-free, fully in-bounds for BOTH halves ----
  for (; e + 8 <= mindeg; e += 8) {
    int s[8];
#pragma unroll
    for (int j = 0; j < 8; ++j) s[j] = sp[e + j];
    float4 xv[8];
#pragma unroll
    for (int j = 0; j < 8; ++j)
      xv[j] = *(const float4*)(xlb + (((unsigned)s[j] << 9) + chb));
    float p[8];
#pragma unroll
    for (int j = 0; j < 8; ++j) { LOGIT(p[j], xv[j]) }
#pragma unroll
    for (int j = 0; j < 8; ++j) p[j] = rowsum16(p[j]);
    float mn = m;
#pragma unroll
    for (int j = 0; j < 8; ++j) mn = fmaxf(mn, p[j]);
    float sc = exp2f(m - mn);
    float w[8];
#pragma unroll
    for (int j = 0; j < 8; ++j) w[j] = exp2f(p[j] - mn);
    acc.x *= sc; acc.y *= sc; acc.z *= sc; acc.w *= sc;
    float ws = 0.f;
#pragma unroll
    for (int j = 0; j < 8; ++j) {
      acc.x = fmaf(w[j], xv[j].x, acc.x);
      acc.y = fmaf(w[j], xv[j].y, acc.y);
      acc.z = fmaf(w[j], xv[j].z, acc.z);
      acc.w = fmaf(w[j], xv[j].w, acc.w);
      ws += w[j];
    }
    l = fmaf(l, sc, ws);
    m = mn;
  }
  // ---- tail: 4 edges/iter, clamped indices + masked logits ----
  int dm1 = deg - 1;
  for (; e < maxdeg; e += 4) {
    int sA = sp[min(e + 0, dm1)];
    int sB = sp[min(e + 1, dm1)];
    int sC = sp[min(e + 2, dm1)];
    int sD = sp[min(e + 3, dm1)];
    float4 xa = *(const float4*)(xlb + (((unsigned)sA << 9) + chb));
    float4 xb = *(const float4*)(xlb + (((unsigned)sB << 9) + chb));
    float4 xc = *(const float4*)(xlb + (((unsigned)sC << 9) + chb));
    float4 xd = *(const float4*)(xlb + (((unsigned)sD << 9) + chb));
    float pa, pb, pc, pd;
    LOGIT(pa, xa) LOGIT(pb, xb) LOGIT(pc, xc) LOGIT(pd, xd)
    pa = rowsum16(pa);
    pb = rowsum16(pb);
    pc = rowsum16(pc);
    pd = rowsum16(pd);
    pa = (e + 0 < deg) ? pa : -1e30f;
    pb = (e + 1 < deg) ? pb : -1e30f;
    pc = (e + 2 < deg) ? pc : -1e30f;
    pd = (e + 3 < deg) ? pd : -1e30f;
    float mn = fmaxf(m, fmaxf(fmaxf(pa, pb), fmaxf(pc, pd)));
    float sc = exp2f(m - mn);
    float wa = exp2f(pa - mn);
    float wb = exp2f(pb - mn);
    float wc = exp2f(pc - mn);
    float wd = exp2f(pd - mn);
    acc.x = fmaf(wd, xd.x, fmaf(wc, xc.x, fmaf(wb, xb.x, fmaf(wa, xa.x, acc.x * sc))));
    acc.y = fmaf(wd, xd.y, fmaf(wc, xc.y, fmaf(wb, xb.y, fmaf(wa, xa.y, acc.y * sc))));
    acc.z = fmaf(wd, xd.z, fmaf(wc, xc.z, fmaf(wb, xb.z, fmaf(wa, xa.z, acc.z * sc))));
    acc.w = fmaf(wd, xd.w, fmaf(wc, xc.w, fmaf(wb, xb.w, fmaf(wa, xa.w, acc.w * sc))));
    l = fmaf(l, sc, wa + wb + wc + wd);
    m = mn;
  }
#undef LOGIT

  float inv = 1.f / (l + 1e-16f);
  float4 b1v = *(const float4*)&b1[ch];
  float4 h;
  h.x = acc.x * inv + b1v.x; h.x = h.x > 0.f ? h.x : expm1f(h.x);
  h.y = acc.y * inv + b1v.y; h.y = h.y > 0.f ? h.y : expm1f(h.y);
  h.z = acc.z * inv + b1v.z; h.z = h.z > 0.f ? h.z : expm1f(h.z);
  h.w = acc.w * inv + b1v.w; h.w = h.w > 0.f ? h.w : expm1f(h.w);

  float4 u0 = *(const float4*)&W2l[ch * 3 + 0];
  float4 u1 = *(const float4*)&W2l[ch * 3 + 4];
  float4 u2 = *(const float4*)&W2l[ch * 3 + 8];
  float al0 = fmaf(h.w, u2.y, fmaf(h.z, u1.z, fmaf(h.y, u0.w, h.x * u0.x)));
  float al1 = fmaf(h.w, u2.z, fmaf(h.z, u1.w, fmaf(h.y, u1.x, h.x * u0.y)));
  float al2 = fmaf(h.w, u2.w, fmaf(h.z, u2.x, fmaf(h.y, u1.y, h.x * u0.z)));
  float4 v0 = *(const float4*)&W2r[ch * 3 + 0];
  float4 v1 = *(const float4*)&W2r[ch * 3 + 4];
  float4 v2 = *(const float4*)&W2r[ch * 3 + 8];
  float ar0 = fmaf(h.w, v2.y, fmaf(h.z, v1.z, fmaf(h.y, v0.w, h.x * v0.x)));
  float ar1 = fmaf(h.w, v2.z, fmaf(h.z, v1.w, fmaf(h.y, v1.x, h.x * v0.y)));
  float ar2 = fmaf(h.w, v2.w, fmaf(h.z, v2.x, fmaf(h.y, v1.y, h.x * v0.z)));
#pragma unroll
  for (int off = 1; off < 32; off <<= 1) {
    al0 += __shfl_xor(al0, off); al1 += __shfl_xor(al1, off);
    al2 += __shfl_xor(al2, off); ar0 += __shfl_xor(ar0, off);
    ar1 += __shfl_xor(ar1, off); ar2 += __shfl_xor(ar2, off);
  }
  if (valid && sub == 0) {
    *(float4*)&xl2[node * 4] = make_float4(al0, al1, al2, 0.f);
    *(float4*)&xr2[node * 4] = make_float4(ar0, ar1, ar2, 0.f);
  }
}

// ---------------------------------------------------------------------------
// fused layer-2 edge phase + mean-pool. 16 lanes per node (= one DPP row);
// per-lane online softmax (exp2 domain) over a 16-stride slice, DPP rotate
// merge of (m,l,acc3) states. Pool pre-reduced in LDS.
__global__ __launch_bounds__(256) void k_fused2(const float* __restrict__ xl2,
                                                const float* __restrict__ xr2,
                                                const int* __restrict__ row_ptr,
                                                const int* __restrict__ csr_src,
                                                const float* __restrict__ att2,
                                                const float* __restrict__ b2,
                                                const int* __restrict__ batch,
                                                float* __restrict__ gsum,
                                                float* __restrict__ gcnt, int n) {
  __shared__ float ls[NGRAPH * 3];
  __shared__ float lc[NGRAPH];
  int t = threadIdx.x;
  for (int i = t; i < NGRAPH * 3; i += 256) ls[i] = 0.f;
  for (int i = t; i < NGRAPH; i += 256) lc[i] = 0.f;
  __syncthreads();

  int node = (blockIdx.x * 256 + t) >> 4;  // 16 nodes per block
  int lane = t & 15;
  if (node < n) {
    float4 xrv = *(const float4*)&xr2[node * 4];
    float c0 = att2[0] * LOG2E, c1 = att2[1] * LOG2E, c2 = att2[2] * LOG2E;
    int s0 = row_ptr[node], s1 = row_ptr[node + 1];
    float m = -1e30f, l = 0.f, a0 = 0.f, a1 = 0.f, a2 = 0.f;
    for (int slot = s0 + lane; slot < s1; slot += 16) {
      int s = csr_src[slot];
      float4 xlv = *(const float4*)&xl2[s * 4];
      float t0 = xlv.x + xrv.x; t0 = fmaxf(t0, 0.2f * t0);
      float t1 = xlv.y + xrv.y; t1 = fmaxf(t1, 0.2f * t1);
      float t2 = xlv.z + xrv.z; t2 = fmaxf(t2, 0.2f * t2);
      float p = fmaf(t2, c2, fmaf(t1, c1, t0 * c0));
      float mn = fmaxf(m, p);
      float sc = exp2f(m - mn);
      float w  = exp2f(p - mn);
      a0 = a0 * sc + w * xlv.x;
      a1 = a1 * sc + w * xlv.y;
      a2 = a2 * sc + w * xlv.z;
      l = l * sc + w;
      m = mn;
    }
#define MERGE(C)                                                        \
    {                                                                   \
      float m2 = DPP_ROR(C, m);                                         \
      float l2 = DPP_ROR(C, l);                                         \
      float b0 = DPP_ROR(C, a0);                                        \
      float b1v = DPP_ROR(C, a1);                                       \
      float b2v = DPP_ROR(C, a2);                                       \
      float mn = fmaxf(m, m2);                                          \
      float sA = exp2f(m - mn);                                         \
      float sB = exp2f(m2 - mn);                                        \
      a0 = a0 * sA + b0 * sB;                                           \
      a1 = a1 * sA + b1v * sB;                                          \
      a2 = a2 * sA + b2v * sB;                                          \
      l = l * sA + l2 * sB;                                             \
      m = mn;                                                           \
    }
    MERGE(8) MERGE(4) MERGE(2) MERGE(1)
#undef MERGE
    if (lane == 0) {
      float inv = 1.f / (l + 1e-16f);
      float o0 = a0 * inv + b2[0];
      float o1 = a1 * inv + b2[1];
      float o2 = a2 * inv + b2[2];
      int b = batch[node];
      atomicAdd(&ls[b * 3 + 0], o0);
      atomicAdd(&ls[b * 3 + 1], o1);
      atomicAdd(&ls[b * 3 + 2], o2);
      atomicAdd(&lc[b], 1.f);
    }
  }
  __syncthreads();
  for (int i = t; i < NGRAPH * 3; i += 256)
    if (ls[i] != 0.f) atomicAdd(&gsum[i], ls[i]);
  for (int i = t; i < NGRAPH; i += 256)
    if (lc[i] != 0.f) atomicAdd(&gcnt[i], lc[i]);
}

// 1 block, 64 threads: per-graph mean + 2-layer MLP
__global__ __launch_bounds__(64) void k_mlp(const float* __restrict__ gsum,
                                            const float* __restrict__ gcnt,
                                            const float* __restrict__ Wr1,
                                            const float* __restrict__ br1,
                                            const float* __restrict__ Wr2,
                                            const float* __restrict__ br2,
                                            float* __restrict__ out) {
  int t = threadIdx.x;
  if (t >= NGRAPH) return;
  float cnt = fmaxf(gcnt[t], 1.f);
  float g0 = gsum[t * 3 + 0] / cnt;
  float g1 = gsum[t * 3 + 1] / cnt;
  float g2 = gsum[t * 3 + 2] / cnt;
  float o0 = br2[0], o1 = br2[1], o2 = br2[2];
  for (int j = 0; j < 64; ++j) {
    float hj = g0 * Wr1[j] + g1 * Wr1[64 + j] + g2 * Wr1[128 + j] + br1[j];
    hj = fmaxf(hj, 0.f);
    o0 = fmaf(hj, Wr2[j * 3 + 0], o0);
    o1 = fmaf(hj, Wr2[j * 3 + 1], o1);
    o2 = fmaf(hj, Wr2[j * 3 + 2], o2);
  }
  out[t * 3 + 0] = o0;
  out[t * 3 + 1] = o1;
  out[t * 3 + 2] = o2;
}

// ---------------------------------------------------------------------------
extern "C" void kernel_launch(void* const* d_in, const int* in_sizes, int n_in,
                              void* d_out, int out_size, void* d_ws, size_t ws_size,
                              hipStream_t stream) {
  const float* x    = (const float*)d_in[0];
  const int*   ei   = (const int*)d_in[1];
  const int*   batch= (const int*)d_in[2];
  const float* W1l  = (const float*)d_in[3];
  const float* W1r  = (const float*)d_in[4];
  const float* att1 = (const float*)d_in[5];
  const float* b1   = (const float*)d_in[6];
  const float* W2l  = (const float*)d_in[7];
  const float* W2r  = (const float*)d_in[8];
  const float* att2 = (const float*)d_in[9];
  const float* b2   = (const float*)d_in[10];
  const float* Wr1  = (const float*)d_in[11];
  const float* br1  = (const float*)d_in[12];
  const float* Wr2  = (const float*)d_in[13];
  const float* br2  = (const float*)d_in[14];
  float* out = (float*)d_out;

  const int N  = in_sizes[0] / 128;
  const int E  = in_sizes[1] / 2;
  const int Et = E + N;

  char* p = (char*)d_ws;
  auto alloc = [&](size_t bytes) -> char* {
    char* r = p;
    p += (bytes + 255) & ~(size_t)255;
    return r;
  };
  float*    xl1    = (float*)alloc((size_t)N * 128 * 4);
  float*    xr1    = (float*)alloc((size_t)N * 128 * 4);
  int*      row_ptr= (int*)alloc((size_t)(N + 1) * 4);
  int*      csr_src= (int*)alloc((size_t)Et * 4);
  // zero-init group (one memset): deg | cursor | gsum | gcnt
  char*     z0     = p;
  int*      deg    = (int*)alloc((size_t)N * 4);
  int*      cursor = (int*)alloc((size_t)N * 4);
  float*    gsum   = (float*)alloc(NGRAPH * 3 * 4);
  float*    gcnt   = (float*)alloc(NGRAPH * 4);
  size_t    zbytes = (size_t)(p - z0);
  float*    xl2    = (float*)alloc((size_t)N * 4 * 4);
  float*    xr2    = (float*)alloc((size_t)N * 4 * 4);

  hipMemsetAsync(z0, 0, zbytes, stream);
  hipLaunchKernelGGL(k_deg, dim3((Et + 255) / 256), dim3(256), 0, stream, ei, E, Et, deg);
  hipLaunchKernelGGL(k_scan, dim3(1), dim3(1024), 0, stream, deg, row_ptr, N);
  hipLaunchKernelGGL(k_fill, dim3((Et + 255) / 256), dim3(256), 0, stream,
                     ei, E, Et, row_ptr, cursor, csr_src);
  hipLaunchKernelGGL(k_gemm128, dim3((N + 63) / 64, 2), dim3(256), 0, stream,
                     x, W1l, W1r, xl1, xr1, N);
  int waves1 = (N + 1) / 2;
  hipLaunchKernelGGL(k_fused1, dim3((waves1 * 64 + 255) / 256), dim3(256), 0, stream,
                     xl1, xr1, row_ptr, csr_src, att1, b1, W2l, W2r, xl2, xr2, N);
  hipLaunchKernelGGL(k_fused2, dim3((N * 16 + 255) / 256), dim3(256), 0, stream,
                     xl2, xr2, row_ptr, csr_src, att2, b2, batch, gsum, gcnt, N);
  hipLaunchKernelGGL(k_mlp, dim3(1), dim3(64), 0, stream,
                     gsum, gcnt, Wr1, br1, Wr2, br2, out);
}